// Round 1
// baseline (14507.642 us; speedup 1.0000x reference)
//
#include <hip/hip_runtime.h>

// Dims (fixed by problem, but read N/E/ED/IN from in_sizes at launch)
#define H2C 256   // 2*hidden
#define HDC 128   // hidden
#define GATEC 64

// ---------------- GEMM: C[M,N] = A[M,K] @ B[K,N], fp32, row-major ----------------
// 64x64 tile, BK=16, 256 threads, 4x4 microtile.
__global__ __launch_bounds__(256)
void gemm_f32(const float* __restrict__ A, const float* __restrict__ B,
              float* __restrict__ C, int M, int N, int K)
{
    const int bn = blockIdx.x * 64;
    const int bm = blockIdx.y * 64;
    const int tid = threadIdx.x;
    __shared__ float As[16][64 + 4];
    __shared__ float Bs[16][64 + 4];
    const int tx = tid & 15;   // col group 0..15
    const int ty = tid >> 4;   // row group 0..15
    float acc[4][4] = {};

    const int ar  = tid >> 2;        // 0..63 (A tile row)
    const int ac4 = (tid & 3) * 4;   // 0,4,8,12 (A tile k-col, float4)
    const int br  = tid >> 4;        // 0..15 (B tile k-row)
    const int bc4 = (tid & 15) * 4;  // 0..60 (B tile col, float4)

    for (int k0 = 0; k0 < K; k0 += 16) {
        {
            const int m = bm + ar;
            float4 v = make_float4(0.f, 0.f, 0.f, 0.f);
            if (m < M) v = *reinterpret_cast<const float4*>(&A[(size_t)m * K + k0 + ac4]);
            As[ac4 + 0][ar] = v.x; As[ac4 + 1][ar] = v.y;
            As[ac4 + 2][ar] = v.z; As[ac4 + 3][ar] = v.w;
        }
        {
            float4 v = *reinterpret_cast<const float4*>(&B[(size_t)(k0 + br) * N + bn + bc4]);
            Bs[br][bc4 + 0] = v.x; Bs[br][bc4 + 1] = v.y;
            Bs[br][bc4 + 2] = v.z; Bs[br][bc4 + 3] = v.w;
        }
        __syncthreads();
        #pragma unroll
        for (int k = 0; k < 16; ++k) {
            float a[4], b[4];
            #pragma unroll
            for (int i = 0; i < 4; ++i) a[i] = As[k][ty * 4 + i];
            #pragma unroll
            for (int j = 0; j < 4; ++j) b[j] = Bs[k][tx * 4 + j];
            #pragma unroll
            for (int i = 0; i < 4; ++i)
                #pragma unroll
                for (int j = 0; j < 4; ++j) acc[i][j] += a[i] * b[j];
        }
        __syncthreads();
    }
    #pragma unroll
    for (int i = 0; i < 4; ++i) {
        const int m = bm + ty * 4 + i;
        if (m < M) {
            #pragma unroll
            for (int j = 0; j < 4; ++j)
                C[(size_t)m * N + bn + tx * 4 + j] = acc[i][j];
        }
    }
}

// ---------------- SpMM scatter: Y[row[e]] += val[e] * X[col[e]] ----------------
// F floats per row; F/4 threads per edge, float4 gather, 4 fp32 atomics.
template <int F>
__global__ __launch_bounds__(256)
void spmm_atomic(const int* __restrict__ row, const int* __restrict__ col,
                 const float* __restrict__ val, const float* __restrict__ X,
                 float* __restrict__ Y, int nE)
{
    const int TPE = F / 4;
    const long long gid = (long long)blockIdx.x * blockDim.x + threadIdx.x;
    const long long e = gid / TPE;
    if (e >= nE) return;
    const int f = (int)(gid % TPE) * 4;
    const int r = row[e];
    const int c = col[e];
    const float v = val[e];
    const float4 x = *reinterpret_cast<const float4*>(&X[(size_t)c * F + f]);
    float* yp = &Y[(size_t)r * F + f];
    unsafeAtomicAdd(yp + 0, v * x.x);
    unsafeAtomicAdd(yp + 1, v * x.y);
    unsafeAtomicAdd(yp + 2, v * x.z);
    unsafeAtomicAdd(yp + 3, v * x.w);
}

// ---------------- activation 1: y = relu(prelu(y + bias, a)) ----------------
__global__ __launch_bounds__(256)
void act1_kernel(float* __restrict__ Y, const float* __restrict__ bias,
                 const float* __restrict__ a, long long n4, int F4)
{
    const float av = a[0];
    long long i = (long long)blockIdx.x * blockDim.x + threadIdx.x;
    const long long stride = (long long)gridDim.x * blockDim.x;
    for (; i < n4; i += stride) {
        float4 y = reinterpret_cast<float4*>(Y)[i];
        const float4 b = reinterpret_cast<const float4*>(bias)[i % F4];
        float t;
        t = y.x + b.x; t = t >= 0.f ? t : av * t; y.x = fmaxf(t, 0.f);
        t = y.y + b.y; t = t >= 0.f ? t : av * t; y.y = fmaxf(t, 0.f);
        t = y.z + b.z; t = t >= 0.f ? t : av * t; y.z = fmaxf(t, 0.f);
        t = y.w + b.w; t = t >= 0.f ? t : av * t; y.w = fmaxf(t, 0.f);
        reinterpret_cast<float4*>(Y)[i] = y;
    }
}

// ---------------- activation 2: y = prelu(y + bias, a) ----------------
__global__ __launch_bounds__(256)
void act2_kernel(float* __restrict__ Y, const float* __restrict__ bias,
                 const float* __restrict__ a, long long n4, int F4)
{
    const float av = a[0];
    long long i = (long long)blockIdx.x * blockDim.x + threadIdx.x;
    const long long stride = (long long)gridDim.x * blockDim.x;
    for (; i < n4; i += stride) {
        float4 y = reinterpret_cast<float4*>(Y)[i];
        const float4 b = reinterpret_cast<const float4*>(bias)[i % F4];
        float t;
        t = y.x + b.x; y.x = t >= 0.f ? t : av * t;
        t = y.y + b.y; y.y = t >= 0.f ? t : av * t;
        t = y.z + b.z; y.z = t >= 0.f ? t : av * t;
        t = y.w + b.w; y.w = t >= 0.f ? t : av * t;
        reinterpret_cast<float4*>(Y)[i] = y;
    }
}

// ---------------- gate precompute: u1 = G1w@G3w[:64], u2 = G2w@G3w[64:128] ----------------
__global__ void gate_pre_kernel(const float* __restrict__ G1w, const float* __restrict__ G1b,
                                const float* __restrict__ G2w, const float* __restrict__ G2b,
                                const float* __restrict__ G3w, const float* __restrict__ G3b,
                                float* __restrict__ U)
{
    const int h = threadIdx.x;  // 0..127
    float s1 = 0.f, s2 = 0.f;
    for (int g = 0; g < GATEC; ++g) {
        s1 += G1w[h * GATEC + g] * G3w[g];
        s2 += G2w[h * GATEC + g] * G3w[GATEC + g];
    }
    U[h] = s1;
    U[HDC + h] = s2;
    if (h == 0) {
        float c = G3b[0];
        for (int g = 0; g < GATEC; ++g)
            c += G1b[g] * G3w[g] + G2b[g] * G3w[GATEC + g];
        U[2 * HDC] = c;
        U[2 * HDC + 1] = G3w[2 * GATEC];  // deg weight
    }
}

// ---------------- beta: sigmoid(h1 . u1 + h3 . u2 + wd*deg + c) ----------------
__global__ __launch_bounds__(256)
void beta_kernel(const float* __restrict__ h1, const float* __restrict__ h3,
                 const float* __restrict__ deg, const float* __restrict__ U,
                 float* __restrict__ beta, int n)
{
    const int i = blockIdx.x * blockDim.x + threadIdx.x;
    if (i >= n) return;
    const float c = U[2 * HDC], wd = U[2 * HDC + 1];
    float s = c + wd * deg[i];
    const float4* h1p = reinterpret_cast<const float4*>(h1 + (size_t)i * HDC);
    const float4* h3p = reinterpret_cast<const float4*>(h3 + (size_t)i * HDC);
    const float4* u1p = reinterpret_cast<const float4*>(U);
    const float4* u2p = reinterpret_cast<const float4*>(U + HDC);
    #pragma unroll 8
    for (int j = 0; j < HDC / 4; ++j) {
        const float4 a = h1p[j], b = u1p[j];
        s += a.x * b.x + a.y * b.y + a.z * b.z + a.w * b.w;
        const float4 a2 = h3p[j], b2 = u2p[j];
        s += a2.x * b2.x + a2.y * b2.y + a2.z * b2.z + a2.w * b2.w;
    }
    beta[i] = 1.f / (1.f + expf(-s));
}

extern "C" void kernel_launch(void* const* d_in, const int* in_sizes, int n_in,
                              void* d_out, int out_size, void* d_ws, size_t ws_size,
                              hipStream_t stream)
{
    const float* x1  = (const float*)d_in[0];
    const float* x2  = (const float*)d_in[1];
    const int*   a1r = (const int*)d_in[2];
    const int*   a1c = (const int*)d_in[3];
    const float* a1v = (const float*)d_in[4];
    const int*   a2r = (const int*)d_in[5];
    const int*   a2c = (const int*)d_in[6];
    const float* a2v = (const float*)d_in[7];
    const int*   dr  = (const int*)d_in[8];
    const int*   dc  = (const int*)d_in[9];
    const float* dv  = (const float*)d_in[10];
    const float* deg = (const float*)d_in[11];
    const float* W0  = (const float*)d_in[12];
    const float* b0  = (const float*)d_in[13];
    const float* a0  = (const float*)d_in[14];
    const float* W1  = (const float*)d_in[15];
    const float* b1  = (const float*)d_in[16];
    const float* a1p = (const float*)d_in[17];
    const float* G1w = (const float*)d_in[18];
    const float* G1b = (const float*)d_in[19];
    const float* G2w = (const float*)d_in[20];
    const float* G2b = (const float*)d_in[21];
    const float* G3w = (const float*)d_in[22];
    const float* G3b = (const float*)d_in[23];

    const int E  = in_sizes[2];
    const int ED = in_sizes[8];
    const int N  = in_sizes[11];
    const int IN = in_sizes[0] / N;

    // workspace layout (floats)
    float* ws  = (float*)d_ws;
    float* XW  = ws;                           // N*H2
    float* Bb  = XW + (size_t)N * H2C;         // N*H2 (spmm1 out / layer-2 input)
    float* Cb  = Bb + (size_t)N * H2C;         // N*H  (layer-2 gemm out)
    float* U   = Cb + (size_t)N * HDC;         // 258

    float* out  = (float*)d_out;
    float* h1   = out;
    float* h2   = out + 1 * (size_t)N * HDC;
    float* h3   = out + 2 * (size_t)N * HDC;
    float* h4   = out + 3 * (size_t)N * HDC;
    float* beta = out + 4 * (size_t)N * HDC;

    gate_pre_kernel<<<1, HDC, 0, stream>>>(G1w, G1b, G2w, G2b, G3w, G3b, U);

    auto run_branch = [&](const int* er, const int* ec, const float* ev, int ne,
                          const float* xw, float* hout) {
        // spmm1 (F=256) + bias/prelu/relu
        hipMemsetAsync(Bb, 0, (size_t)N * H2C * sizeof(float), stream);
        {
            const long long tot = (long long)ne * (H2C / 4);
            spmm_atomic<H2C><<<dim3((unsigned)((tot + 255) / 256)), 256, 0, stream>>>(
                er, ec, ev, xw, Bb, ne);
        }
        {
            const long long n4 = (long long)N * (H2C / 4);
            act1_kernel<<<dim3(2048), 256, 0, stream>>>(Bb, b0, a0, n4, H2C / 4);
        }
        // layer-2 GEMM: Cb = Bb @ W1  (N x 128)
        gemm_f32<<<dim3(HDC / 64, (N + 63) / 64), 256, 0, stream>>>(Bb, W1, Cb, N, HDC, H2C);
        // spmm2 (F=128) into hout + bias/prelu
        hipMemsetAsync(hout, 0, (size_t)N * HDC * sizeof(float), stream);
        {
            const long long tot = (long long)ne * (HDC / 4);
            spmm_atomic<HDC><<<dim3((unsigned)((tot + 255) / 256)), 256, 0, stream>>>(
                er, ec, ev, Cb, hout, ne);
        }
        {
            const long long n4 = (long long)N * (HDC / 4);
            act2_kernel<<<dim3(2048), 256, 0, stream>>>(hout, b1, a1p, n4, HDC / 4);
        }
    };

    // XW = x1 @ W0 (shared by h1, h3, h4)
    gemm_f32<<<dim3(H2C / 64, (N + 63) / 64), 256, 0, stream>>>(x1, W0, XW, N, H2C, IN);
    run_branch(a1r, a1c, a1v, E, XW, h1);
    run_branch(a2r, a2c, a2v, E, XW, h3);
    run_branch(dr, dc, dv, ED, XW, h4);

    // XW = x2 @ W0 (h2 only)
    gemm_f32<<<dim3(H2C / 64, (N + 63) / 64), 256, 0, stream>>>(x2, W0, XW, N, H2C, IN);
    run_branch(a1r, a1c, a1v, E, XW, h2);

    beta_kernel<<<dim3((N + 255) / 256), 256, 0, stream>>>(h1, h3, deg, U, beta, N);
}

// Round 2
// 1350.919 us; speedup vs baseline: 10.7391x; 10.7391x over previous
//
#include <hip/hip_runtime.h>
#include <hip/hip_bf16.h>

#define H2C 256   // 2*hidden
#define HDC 128   // hidden
#define GATEC 64

__device__ inline float bf2f(unsigned short v) {
    union { unsigned u; float f; } t; t.u = ((unsigned)v) << 16; return t.f;
}
__device__ inline unsigned short f2bf(float v) {
    __hip_bfloat16 b = __float2bfloat16(v);
    return *reinterpret_cast<unsigned short*>(&b);
}

// ---------------- GEMM: C[M,N] = A[M,K] @ B[K,N], fp32 compute ----------------
// 64x64 tile, BK=16, 256 threads, 4x4 microtile. OutT = float or bf16(ushort).
template <typename OutT>
__global__ __launch_bounds__(256)
void gemm_f32(const float* __restrict__ A, const float* __restrict__ B,
              OutT* __restrict__ C, int M, int Nn, int K)
{
    const int bn = blockIdx.x * 64;
    const int bm = blockIdx.y * 64;
    const int tid = threadIdx.x;
    __shared__ float As[16][64 + 4];
    __shared__ float Bs[16][64 + 4];
    const int tx = tid & 15;
    const int ty = tid >> 4;
    float acc[4][4] = {};

    const int ar  = tid >> 2;
    const int ac4 = (tid & 3) * 4;
    const int br  = tid >> 4;
    const int bc4 = (tid & 15) * 4;

    for (int k0 = 0; k0 < K; k0 += 16) {
        {
            const int m = bm + ar;
            float4 v = make_float4(0.f, 0.f, 0.f, 0.f);
            if (m < M) v = *reinterpret_cast<const float4*>(&A[(size_t)m * K + k0 + ac4]);
            As[ac4 + 0][ar] = v.x; As[ac4 + 1][ar] = v.y;
            As[ac4 + 2][ar] = v.z; As[ac4 + 3][ar] = v.w;
        }
        {
            float4 v = *reinterpret_cast<const float4*>(&B[(size_t)(k0 + br) * Nn + bn + bc4]);
            Bs[br][bc4 + 0] = v.x; Bs[br][bc4 + 1] = v.y;
            Bs[br][bc4 + 2] = v.z; Bs[br][bc4 + 3] = v.w;
        }
        __syncthreads();
        #pragma unroll
        for (int k = 0; k < 16; ++k) {
            float a[4], b[4];
            #pragma unroll
            for (int i = 0; i < 4; ++i) a[i] = As[k][ty * 4 + i];
            #pragma unroll
            for (int j = 0; j < 4; ++j) b[j] = Bs[k][tx * 4 + j];
            #pragma unroll
            for (int i = 0; i < 4; ++i)
                #pragma unroll
                for (int j = 0; j < 4; ++j) acc[i][j] += a[i] * b[j];
        }
        __syncthreads();
    }
    #pragma unroll
    for (int i = 0; i < 4; ++i) {
        const int m = bm + ty * 4 + i;
        if (m < M) {
            if constexpr (sizeof(OutT) == 2) {
                ushort4 o;
                o.x = f2bf(acc[i][0]); o.y = f2bf(acc[i][1]);
                o.z = f2bf(acc[i][2]); o.w = f2bf(acc[i][3]);
                *reinterpret_cast<ushort4*>(&C[(size_t)m * Nn + bn + tx * 4]) = o;
            } else {
                float4 o = make_float4(acc[i][0], acc[i][1], acc[i][2], acc[i][3]);
                *reinterpret_cast<float4*>(&C[(size_t)m * Nn + bn + tx * 4]) = o;
            }
        }
    }
}

// ---------------- CSR build ----------------
__global__ __launch_bounds__(256)
void hist_kernel(const int* __restrict__ row, int ne, int* __restrict__ cnt)
{
    long long i = (long long)blockIdx.x * blockDim.x + threadIdx.x;
    if (i < ne) atomicAdd(&cnt[row[i]], 1);
}

__global__ __launch_bounds__(256)
void block_sum_kernel(const int* __restrict__ cnt, int n, int* __restrict__ bsum)
{
    __shared__ int s[256];
    const int tid = threadIdx.x;
    const int i = blockIdx.x * 256 + tid;
    s[tid] = (i < n) ? cnt[i] : 0;
    __syncthreads();
    for (int o = 128; o > 0; o >>= 1) {
        if (tid < o) s[tid] += s[tid + o];
        __syncthreads();
    }
    if (tid == 0) bsum[blockIdx.x] = s[0];
}

__global__ void scan_bsum_kernel(int* __restrict__ bsum, int nb)
{
    if (threadIdx.x == 0) {
        int acc = 0;
        for (int b = 0; b < nb; ++b) { int t = bsum[b]; bsum[b] = acc; acc += t; }
    }
}

__global__ __launch_bounds__(256)
void block_scan_kernel(const int* __restrict__ cnt, int n, const int* __restrict__ bsum,
                       int* __restrict__ rp, int ne)
{
    __shared__ int sh[256];
    const int tid = threadIdx.x;
    const int i = blockIdx.x * 256 + tid;
    const int v = (i < n) ? cnt[i] : 0;
    sh[tid] = v;
    __syncthreads();
    for (int o = 1; o < 256; o <<= 1) {
        int t = 0;
        if (tid >= o) t = sh[tid - o];
        __syncthreads();
        sh[tid] += t;
        __syncthreads();
    }
    if (i < n) rp[i] = bsum[blockIdx.x] + sh[tid] - v;  // exclusive
    if (i == 0) rp[n] = ne;
}

__global__ __launch_bounds__(256)
void copy_int_kernel(const int* __restrict__ src, int* __restrict__ dst, int n)
{
    const int i = blockIdx.x * 256 + threadIdx.x;
    if (i < n) dst[i] = src[i];
}

__global__ __launch_bounds__(256)
void scatter_kernel(const int* __restrict__ row, const int* __restrict__ col,
                    const float* __restrict__ val, int ne,
                    int* __restrict__ cursor, int* __restrict__ ci, float* __restrict__ cv)
{
    long long i = (long long)blockIdx.x * blockDim.x + threadIdx.x;
    if (i >= ne) return;
    const int r = row[i];
    const int p = atomicAdd(&cursor[r], 1);
    ci[p] = col[i];
    cv[p] = val[i];
}

// ---------------- CSR SpMM, F=256, fused bias+PReLU+ReLU, bf16 gather ----------------
__global__ __launch_bounds__(256)
void spmm_csr_f256(const int* __restrict__ rp, const int* __restrict__ ci,
                   const float* __restrict__ cv, const unsigned short* __restrict__ X,
                   float* __restrict__ Y, const float* __restrict__ bias,
                   const float* __restrict__ ap, int n)
{
    const int r = blockIdx.x * 4 + (threadIdx.x >> 6);
    if (r >= n) return;
    const int lane = threadIdx.x & 63;
    const int s = rp[r], e = rp[r + 1];
    float4 acc = make_float4(0.f, 0.f, 0.f, 0.f);
    for (int j = s; j < e; ++j) {
        const int c = ci[j];
        const float v = cv[j];
        const ushort4 xb = *reinterpret_cast<const ushort4*>(X + (size_t)c * H2C + lane * 4);
        acc.x += v * bf2f(xb.x); acc.y += v * bf2f(xb.y);
        acc.z += v * bf2f(xb.z); acc.w += v * bf2f(xb.w);
    }
    const float a = ap[0];
    const float4 b = *reinterpret_cast<const float4*>(bias + lane * 4);
    float t;
    t = acc.x + b.x; t = t >= 0.f ? t : a * t; acc.x = fmaxf(t, 0.f);
    t = acc.y + b.y; t = t >= 0.f ? t : a * t; acc.y = fmaxf(t, 0.f);
    t = acc.z + b.z; t = t >= 0.f ? t : a * t; acc.z = fmaxf(t, 0.f);
    t = acc.w + b.w; t = t >= 0.f ? t : a * t; acc.w = fmaxf(t, 0.f);
    *reinterpret_cast<float4*>(Y + (size_t)r * H2C + lane * 4) = acc;
}

// ---------------- CSR SpMM, F=128, fused bias+PReLU, bf16 gather ----------------
__global__ __launch_bounds__(256)
void spmm_csr_f128(const int* __restrict__ rp, const int* __restrict__ ci,
                   const float* __restrict__ cv, const unsigned short* __restrict__ X,
                   float* __restrict__ Y, const float* __restrict__ bias,
                   const float* __restrict__ ap, int n)
{
    const int r = blockIdx.x * 4 + (threadIdx.x >> 6);
    if (r >= n) return;
    const int lane = threadIdx.x & 63;
    const int s = rp[r], e = rp[r + 1];
    float ax = 0.f, ay = 0.f;
    for (int j = s; j < e; ++j) {
        const int c = ci[j];
        const float v = cv[j];
        const unsigned xb = *reinterpret_cast<const unsigned*>(X + (size_t)c * HDC + lane * 2);
        ax += v * bf2f((unsigned short)(xb & 0xffffu));
        ay += v * bf2f((unsigned short)(xb >> 16));
    }
    const float a = ap[0];
    ax += bias[lane * 2 + 0];
    ay += bias[lane * 2 + 1];
    ax = ax >= 0.f ? ax : a * ax;
    ay = ay >= 0.f ? ay : a * ay;
    *reinterpret_cast<float2*>(Y + (size_t)r * HDC + lane * 2) = make_float2(ax, ay);
}

// ---------------- gate precompute ----------------
__global__ void gate_pre_kernel(const float* __restrict__ G1w, const float* __restrict__ G1b,
                                const float* __restrict__ G2w, const float* __restrict__ G2b,
                                const float* __restrict__ G3w, const float* __restrict__ G3b,
                                float* __restrict__ U)
{
    const int h = threadIdx.x;  // 0..127
    float s1 = 0.f, s2 = 0.f;
    for (int g = 0; g < GATEC; ++g) {
        s1 += G1w[h * GATEC + g] * G3w[g];
        s2 += G2w[h * GATEC + g] * G3w[GATEC + g];
    }
    U[h] = s1;
    U[HDC + h] = s2;
    if (h == 0) {
        float c = G3b[0];
        for (int g = 0; g < GATEC; ++g)
            c += G1b[g] * G3w[g] + G2b[g] * G3w[GATEC + g];
        U[2 * HDC] = c;
        U[2 * HDC + 1] = G3w[2 * GATEC];
    }
}

// ---------------- beta ----------------
__global__ __launch_bounds__(256)
void beta_kernel(const float* __restrict__ h1, const float* __restrict__ h3,
                 const float* __restrict__ deg, const float* __restrict__ U,
                 float* __restrict__ beta, int n)
{
    const int i = blockIdx.x * blockDim.x + threadIdx.x;
    if (i >= n) return;
    const float c = U[2 * HDC], wd = U[2 * HDC + 1];
    float s = c + wd * deg[i];
    const float4* h1p = reinterpret_cast<const float4*>(h1 + (size_t)i * HDC);
    const float4* h3p = reinterpret_cast<const float4*>(h3 + (size_t)i * HDC);
    const float4* u1p = reinterpret_cast<const float4*>(U);
    const float4* u2p = reinterpret_cast<const float4*>(U + HDC);
    #pragma unroll 8
    for (int j = 0; j < HDC / 4; ++j) {
        const float4 a = h1p[j], b = u1p[j];
        s += a.x * b.x + a.y * b.y + a.z * b.z + a.w * b.w;
        const float4 a2 = h3p[j], b2 = u2p[j];
        s += a2.x * b2.x + a2.y * b2.y + a2.z * b2.z + a2.w * b2.w;
    }
    beta[i] = 1.f / (1.f + expf(-s));
}

extern "C" void kernel_launch(void* const* d_in, const int* in_sizes, int n_in,
                              void* d_out, int out_size, void* d_ws, size_t ws_size,
                              hipStream_t stream)
{
    const float* x1  = (const float*)d_in[0];
    const float* x2  = (const float*)d_in[1];
    const int*   a1r = (const int*)d_in[2];
    const int*   a1c = (const int*)d_in[3];
    const float* a1v = (const float*)d_in[4];
    const int*   a2r = (const int*)d_in[5];
    const int*   a2c = (const int*)d_in[6];
    const float* a2v = (const float*)d_in[7];
    const int*   dr  = (const int*)d_in[8];
    const int*   dc  = (const int*)d_in[9];
    const float* dv  = (const float*)d_in[10];
    const float* deg = (const float*)d_in[11];
    const float* W0  = (const float*)d_in[12];
    const float* b0  = (const float*)d_in[13];
    const float* a0  = (const float*)d_in[14];
    const float* W1  = (const float*)d_in[15];
    const float* b1  = (const float*)d_in[16];
    const float* a1p = (const float*)d_in[17];
    const float* G1w = (const float*)d_in[18];
    const float* G1b = (const float*)d_in[19];
    const float* G2w = (const float*)d_in[20];
    const float* G2b = (const float*)d_in[21];
    const float* G3w = (const float*)d_in[22];
    const float* G3b = (const float*)d_in[23];

    const int E  = in_sizes[2];
    const int ED = in_sizes[8];
    const int N  = in_sizes[11];
    const int IN = in_sizes[0] / N;

    // ---- workspace bump allocator (256 B aligned) ----
    char* base = (char*)d_ws;
    size_t off = 0;
    auto alloc = [&](size_t bytes) -> char* {
        char* p = base + off;
        off += (bytes + 255) & ~(size_t)255;
        return p;
    };
    unsigned short* XWb = (unsigned short*)alloc((size_t)N * H2C * 2);  // bf16 x@W0
    float*          Bb  = (float*)alloc((size_t)N * H2C * 4);           // fp32 layer-1 act
    unsigned short* Cbb = (unsigned short*)alloc((size_t)N * HDC * 2);  // bf16 layer-2 gemm out
    float*          U   = (float*)alloc(258 * 4);
    int* rp1    = (int*)alloc((size_t)(N + 1) * 4);
    int* rp2    = (int*)alloc((size_t)(N + 1) * 4);
    int* rpD    = (int*)alloc((size_t)(N + 1) * 4);
    int* cursor = (int*)alloc((size_t)(N + 1) * 4);
    int* bsum   = (int*)alloc(1024 * 4);
    int*   ci1 = (int*)alloc((size_t)E * 4);
    float* cv1 = (float*)alloc((size_t)E * 4);
    int*   ci2 = (int*)alloc((size_t)E * 4);
    float* cv2 = (float*)alloc((size_t)E * 4);
    int*   ciD = (int*)alloc((size_t)ED * 4);
    float* cvD = (float*)alloc((size_t)ED * 4);

    float* out  = (float*)d_out;
    float* h1   = out;
    float* h2   = out + 1 * (size_t)N * HDC;
    float* h3   = out + 2 * (size_t)N * HDC;
    float* h4   = out + 3 * (size_t)N * HDC;
    float* beta = out + 4 * (size_t)N * HDC;

    const int nb = (N + 255) / 256;

    auto build_csr = [&](const int* row, const int* col, const float* val, int ne,
                         int* rp, int* ci, float* cv) {
        hipMemsetAsync(cursor, 0, (size_t)N * 4, stream);
        hist_kernel<<<dim3((ne + 255) / 256), 256, 0, stream>>>(row, ne, cursor);
        block_sum_kernel<<<dim3(nb), 256, 0, stream>>>(cursor, N, bsum);
        scan_bsum_kernel<<<1, 64, 0, stream>>>(bsum, nb);
        block_scan_kernel<<<dim3(nb), 256, 0, stream>>>(cursor, N, bsum, rp, ne);
        copy_int_kernel<<<dim3(nb), 256, 0, stream>>>(rp, cursor, N);
        scatter_kernel<<<dim3((ne + 255) / 256), 256, 0, stream>>>(row, col, val, ne, cursor, ci, cv);
    };

    gate_pre_kernel<<<1, HDC, 0, stream>>>(G1w, G1b, G2w, G2b, G3w, G3b, U);

    build_csr(a1r, a1c, a1v, E,  rp1, ci1, cv1);
    build_csr(a2r, a2c, a2v, E,  rp2, ci2, cv2);
    build_csr(dr,  dc,  dv,  ED, rpD, ciD, cvD);

    auto run_branch = [&](const int* rp, const int* ci, const float* cv, float* hout) {
        spmm_csr_f256<<<dim3((N + 3) / 4), 256, 0, stream>>>(rp, ci, cv, XWb, Bb, b0, a0, N);
        gemm_f32<unsigned short><<<dim3(HDC / 64, (N + 63) / 64), 256, 0, stream>>>(
            Bb, W1, Cbb, N, HDC, H2C);
        spmm_csr_f128<<<dim3((N + 3) / 4), 256, 0, stream>>>(rp, ci, cv, Cbb, hout, b1, a1p, N);
    };

    // XW = bf16(x1 @ W0) shared by h1, h3, h4
    gemm_f32<unsigned short><<<dim3(H2C / 64, (N + 63) / 64), 256, 0, stream>>>(
        x1, W0, XWb, N, H2C, IN);
    run_branch(rp1, ci1, cv1, h1);
    run_branch(rp2, ci2, cv2, h3);
    run_branch(rpD, ciD, cvD, h4);

    // XW = bf16(x2 @ W0), h2 only
    gemm_f32<unsigned short><<<dim3(H2C / 64, (N + 63) / 64), 256, 0, stream>>>(
        x2, W0, XWb, N, H2C, IN);
    run_branch(rp1, ci1, cv1, h2);

    beta_kernel<<<dim3((N + 255) / 256), 256, 0, stream>>>(h1, h3, deg, U, beta, N);
}

// Round 3
// 1063.551 us; speedup vs baseline: 13.6408x; 1.2702x over previous
//
#include <hip/hip_runtime.h>
#include <hip/hip_bf16.h>

#define H2C 256   // 2*hidden
#define HDC 128   // hidden
#define GATEC 64

typedef unsigned short ushort_t;
typedef __attribute__((ext_vector_type(8))) __bf16 bf16x8;
typedef __attribute__((ext_vector_type(4))) float f32x4;

__device__ inline float bf2f(unsigned short v) {
    union { unsigned u; float f; } t; t.u = ((unsigned)v) << 16; return t.f;
}
__device__ inline unsigned short f2bf(float v) {
    __hip_bfloat16 b = __float2bfloat16(v);
    return *reinterpret_cast<unsigned short*>(&b);
}

__device__ inline void gload_lds16(const void* g, void* l) {
    __builtin_amdgcn_global_load_lds(
        (const __attribute__((address_space(1))) unsigned int*)g,
        (__attribute__((address_space(3))) unsigned int*)l, 16, 0, 0);
}

// ---------------- bf16 MFMA GEMM: C[M,Nn] = A[M,K] @ B, B given as BT[Nn,K] ----------------
// All bf16 in, bf16 out, fp32 accum. BM=128, BN=128, BK=64, 256 threads (4 waves, 2x2).
// LDS tiles [rows][64] bf16, XOR-swizzled 16B slots: phys slot = s ^ (r&7).
__global__ __launch_bounds__(256)
void gemm_bf16_mfma(const ushort_t* __restrict__ A, const ushort_t* __restrict__ BT,
                    ushort_t* __restrict__ C, int M, int Nn, int K)
{
    __shared__ ushort_t Alds[128 * 64];
    __shared__ ushort_t Blds[128 * 64];
    const int tid  = threadIdx.x;
    const int w    = tid >> 6;
    const int lane = tid & 63;
    const int wr   = w >> 1;         // 0..1
    const int wc   = w & 1;          // 0..1
    const int bm   = blockIdx.y * 128;
    const int bn   = blockIdx.x * 128;

    f32x4 acc[4][4] = {};

    // per-lane staging coords (16B units): lin = i*256 + tid ; r=lin>>3, p=lin&7
    for (int k0 = 0; k0 < K; k0 += 64) {
        #pragma unroll
        for (int i = 0; i < 4; ++i) {
            const int lin = i * 256 + tid;
            const int r = lin >> 3, p = lin & 7;
            int rm = bm + r; if (rm >= M) rm = M - 1;
            const ushort_t* ga = A + (size_t)rm * K + k0 + ((p ^ (r & 7)) << 3);
            gload_lds16(ga, &Alds[i * 2048 + w * 512]);
        }
        #pragma unroll
        for (int i = 0; i < 4; ++i) {
            const int lin = i * 256 + tid;
            const int r = lin >> 3, p = lin & 7;
            const ushort_t* gb = BT + (size_t)(bn + r) * K + k0 + ((p ^ (r & 7)) << 3);
            gload_lds16(gb, &Blds[i * 2048 + w * 512]);
        }
        __syncthreads();
        #pragma unroll
        for (int kk = 0; kk < 2; ++kk) {
            bf16x8 af[4], bfr[4];
            #pragma unroll
            for (int m = 0; m < 4; ++m) {
                const int r = wr * 64 + m * 16 + (lane & 15);
                const int s = kk * 4 + (lane >> 4);
                af[m] = *reinterpret_cast<const bf16x8*>(&Alds[r * 64 + ((s ^ (r & 7)) << 3)]);
            }
            #pragma unroll
            for (int n = 0; n < 4; ++n) {
                const int r = wc * 64 + n * 16 + (lane & 15);
                const int s = kk * 4 + (lane >> 4);
                bfr[n] = *reinterpret_cast<const bf16x8*>(&Blds[r * 64 + ((s ^ (r & 7)) << 3)]);
            }
            #pragma unroll
            for (int m = 0; m < 4; ++m)
                #pragma unroll
                for (int n = 0; n < 4; ++n)
                    acc[m][n] = __builtin_amdgcn_mfma_f32_16x16x32_bf16(
                        af[m], bfr[n], acc[m][n], 0, 0, 0);
        }
        __syncthreads();
    }

    // epilogue: C row = bm + wr*64 + m*16 + (lane>>4)*4 + q ; col = bn + wc*64 + n*16 + (lane&15)
    #pragma unroll
    for (int m = 0; m < 4; ++m) {
        const int row0 = bm + wr * 64 + m * 16 + ((lane >> 4) << 2);
        #pragma unroll
        for (int n = 0; n < 4; ++n) {
            const int col = bn + wc * 64 + n * 16 + (lane & 15);
            #pragma unroll
            for (int q = 0; q < 4; ++q) {
                const int row = row0 + q;
                if (row < M) C[(size_t)row * Nn + col] = f2bf(acc[m][n][q]);
            }
        }
    }
}

// ---------------- fp32 -> bf16 convert ----------------
__global__ __launch_bounds__(256)
void f2bf_kernel(const float* __restrict__ in, ushort_t* __restrict__ out, long long n4)
{
    long long i = (long long)blockIdx.x * blockDim.x + threadIdx.x;
    const long long stride = (long long)gridDim.x * blockDim.x;
    for (; i < n4; i += stride) {
        const float4 v = reinterpret_cast<const float4*>(in)[i];
        ushort4 o;
        o.x = f2bf(v.x); o.y = f2bf(v.y); o.z = f2bf(v.z); o.w = f2bf(v.w);
        reinterpret_cast<ushort4*>(out)[i] = o;
    }
}

// ---------------- W[R,C] -> bf16 WT[C,R] ----------------
__global__ __launch_bounds__(256)
void transpose_f2bf_kernel(const float* __restrict__ W, ushort_t* __restrict__ WT, int R, int Ccols)
{
    const int i = blockIdx.x * blockDim.x + threadIdx.x;
    if (i >= R * Ccols) return;
    const int c = i / R, r = i % R;
    WT[(size_t)c * R + r] = f2bf(W[(size_t)r * Ccols + c]);
}

// ---------------- CSR build ----------------
__global__ __launch_bounds__(256)
void hist_kernel(const int* __restrict__ row, int ne, int* __restrict__ cnt)
{
    long long i = (long long)blockIdx.x * blockDim.x + threadIdx.x;
    if (i < ne) atomicAdd(&cnt[row[i]], 1);
}

__global__ __launch_bounds__(256)
void block_sum_kernel(const int* __restrict__ cnt, int n, int* __restrict__ bsum)
{
    __shared__ int s[256];
    const int tid = threadIdx.x;
    const int i = blockIdx.x * 256 + tid;
    s[tid] = (i < n) ? cnt[i] : 0;
    __syncthreads();
    for (int o = 128; o > 0; o >>= 1) {
        if (tid < o) s[tid] += s[tid + o];
        __syncthreads();
    }
    if (tid == 0) bsum[blockIdx.x] = s[0];
}

__global__ void scan_bsum_kernel(int* __restrict__ bsum, int nb)
{
    if (threadIdx.x == 0) {
        int acc = 0;
        for (int b = 0; b < nb; ++b) { int t = bsum[b]; bsum[b] = acc; acc += t; }
    }
}

__global__ __launch_bounds__(256)
void block_scan_kernel(const int* __restrict__ cnt, int n, const int* __restrict__ bsum,
                       int* __restrict__ rp, int ne)
{
    __shared__ int sh[256];
    const int tid = threadIdx.x;
    const int i = blockIdx.x * 256 + tid;
    const int v = (i < n) ? cnt[i] : 0;
    sh[tid] = v;
    __syncthreads();
    for (int o = 1; o < 256; o <<= 1) {
        int t = 0;
        if (tid >= o) t = sh[tid - o];
        __syncthreads();
        sh[tid] += t;
        __syncthreads();
    }
    if (i < n) rp[i] = bsum[blockIdx.x] + sh[tid] - v;  // exclusive
    if (i == 0) rp[n] = ne;
}

__global__ __launch_bounds__(256)
void copy_int_kernel(const int* __restrict__ src, int* __restrict__ dst, int n)
{
    const int i = blockIdx.x * 256 + threadIdx.x;
    if (i < n) dst[i] = src[i];
}

__global__ __launch_bounds__(256)
void scatter_kernel(const int* __restrict__ row, const int* __restrict__ col,
                    const float* __restrict__ val, int ne,
                    int* __restrict__ cursor, int* __restrict__ ci, float* __restrict__ cv)
{
    long long i = (long long)blockIdx.x * blockDim.x + threadIdx.x;
    if (i >= ne) return;
    const int r = row[i];
    const int p = atomicAdd(&cursor[r], 1);
    ci[p] = col[i];
    cv[p] = val[i];
}

// ---------------- CSR SpMM, F=256, fused bias+PReLU+ReLU, bf16 in/out ----------------
__global__ __launch_bounds__(256)
void spmm_csr_f256(const int* __restrict__ rp, const int* __restrict__ ci,
                   const float* __restrict__ cv, const ushort_t* __restrict__ X,
                   ushort_t* __restrict__ Y, const float* __restrict__ bias,
                   const float* __restrict__ ap, int n)
{
    const int r = blockIdx.x * 4 + (threadIdx.x >> 6);
    if (r >= n) return;
    const int lane = threadIdx.x & 63;
    const int s = rp[r], e = rp[r + 1];
    float4 acc = make_float4(0.f, 0.f, 0.f, 0.f);
    for (int j = s; j < e; ++j) {
        const int c = ci[j];
        const float v = cv[j];
        const ushort4 xb = *reinterpret_cast<const ushort4*>(X + (size_t)c * H2C + lane * 4);
        acc.x += v * bf2f(xb.x); acc.y += v * bf2f(xb.y);
        acc.z += v * bf2f(xb.z); acc.w += v * bf2f(xb.w);
    }
    const float a = ap[0];
    const float4 b = *reinterpret_cast<const float4*>(bias + lane * 4);
    float t;
    ushort4 o;
    t = acc.x + b.x; t = t >= 0.f ? t : a * t; o.x = f2bf(fmaxf(t, 0.f));
    t = acc.y + b.y; t = t >= 0.f ? t : a * t; o.y = f2bf(fmaxf(t, 0.f));
    t = acc.z + b.z; t = t >= 0.f ? t : a * t; o.z = f2bf(fmaxf(t, 0.f));
    t = acc.w + b.w; t = t >= 0.f ? t : a * t; o.w = f2bf(fmaxf(t, 0.f));
    *reinterpret_cast<ushort4*>(Y + (size_t)r * H2C + lane * 4) = o;
}

// ---------------- CSR SpMM, F=128, fused bias+PReLU, bf16 gather, fp32 out ----------------
__global__ __launch_bounds__(256)
void spmm_csr_f128(const int* __restrict__ rp, const int* __restrict__ ci,
                   const float* __restrict__ cv, const ushort_t* __restrict__ X,
                   float* __restrict__ Y, const float* __restrict__ bias,
                   const float* __restrict__ ap, int n)
{
    const int r = blockIdx.x * 4 + (threadIdx.x >> 6);
    if (r >= n) return;
    const int lane = threadIdx.x & 63;
    const int s = rp[r], e = rp[r + 1];
    float ax = 0.f, ay = 0.f;
    for (int j = s; j < e; ++j) {
        const int c = ci[j];
        const float v = cv[j];
        const unsigned xb = *reinterpret_cast<const unsigned*>(X + (size_t)c * HDC + lane * 2);
        ax += v * bf2f((unsigned short)(xb & 0xffffu));
        ay += v * bf2f((unsigned short)(xb >> 16));
    }
    const float a = ap[0];
    ax += bias[lane * 2 + 0];
    ay += bias[lane * 2 + 1];
    ax = ax >= 0.f ? ax : a * ax;
    ay = ay >= 0.f ? ay : a * ay;
    *reinterpret_cast<float2*>(Y + (size_t)r * HDC + lane * 2) = make_float2(ax, ay);
}

// ---------------- gate precompute ----------------
__global__ void gate_pre_kernel(const float* __restrict__ G1w, const float* __restrict__ G1b,
                                const float* __restrict__ G2w, const float* __restrict__ G2b,
                                const float* __restrict__ G3w, const float* __restrict__ G3b,
                                float* __restrict__ U)
{
    const int h = threadIdx.x;  // 0..127
    float s1 = 0.f, s2 = 0.f;
    for (int g = 0; g < GATEC; ++g) {
        s1 += G1w[h * GATEC + g] * G3w[g];
        s2 += G2w[h * GATEC + g] * G3w[GATEC + g];
    }
    U[h] = s1;
    U[HDC + h] = s2;
    if (h == 0) {
        float c = G3b[0];
        for (int g = 0; g < GATEC; ++g)
            c += G1b[g] * G3w[g] + G2b[g] * G3w[GATEC + g];
        U[2 * HDC] = c;
        U[2 * HDC + 1] = G3w[2 * GATEC];
    }
}

// ---------------- beta ----------------
__global__ __launch_bounds__(256)
void beta_kernel(const float* __restrict__ h1, const float* __restrict__ h3,
                 const float* __restrict__ deg, const float* __restrict__ U,
                 float* __restrict__ beta, int n)
{
    const int i = blockIdx.x * blockDim.x + threadIdx.x;
    if (i >= n) return;
    const float c = U[2 * HDC], wd = U[2 * HDC + 1];
    float s = c + wd * deg[i];
    const float4* h1p = reinterpret_cast<const float4*>(h1 + (size_t)i * HDC);
    const float4* h3p = reinterpret_cast<const float4*>(h3 + (size_t)i * HDC);
    const float4* u1p = reinterpret_cast<const float4*>(U);
    const float4* u2p = reinterpret_cast<const float4*>(U + HDC);
    #pragma unroll 8
    for (int j = 0; j < HDC / 4; ++j) {
        const float4 a = h1p[j], b = u1p[j];
        s += a.x * b.x + a.y * b.y + a.z * b.z + a.w * b.w;
        const float4 a2 = h3p[j], b2 = u2p[j];
        s += a2.x * b2.x + a2.y * b2.y + a2.z * b2.z + a2.w * b2.w;
    }
    beta[i] = 1.f / (1.f + expf(-s));
}

extern "C" void kernel_launch(void* const* d_in, const int* in_sizes, int n_in,
                              void* d_out, int out_size, void* d_ws, size_t ws_size,
                              hipStream_t stream)
{
    const float* x1  = (const float*)d_in[0];
    const float* x2  = (const float*)d_in[1];
    const int*   a1r = (const int*)d_in[2];
    const int*   a1c = (const int*)d_in[3];
    const float* a1v = (const float*)d_in[4];
    const int*   a2r = (const int*)d_in[5];
    const int*   a2c = (const int*)d_in[6];
    const float* a2v = (const float*)d_in[7];
    const int*   dr  = (const int*)d_in[8];
    const int*   dc  = (const int*)d_in[9];
    const float* dv  = (const float*)d_in[10];
    const float* deg = (const float*)d_in[11];
    const float* W0  = (const float*)d_in[12];
    const float* b0  = (const float*)d_in[13];
    const float* a0  = (const float*)d_in[14];
    const float* W1  = (const float*)d_in[15];
    const float* b1  = (const float*)d_in[16];
    const float* a1p = (const float*)d_in[17];
    const float* G1w = (const float*)d_in[18];
    const float* G1b = (const float*)d_in[19];
    const float* G2w = (const float*)d_in[20];
    const float* G2b = (const float*)d_in[21];
    const float* G3w = (const float*)d_in[22];
    const float* G3b = (const float*)d_in[23];

    const int E  = in_sizes[2];
    const int ED = in_sizes[8];
    const int N  = in_sizes[11];
    const int IN = in_sizes[0] / N;   // 256 == H2C (used as K throughout)

    // ---- workspace bump allocator (256 B aligned) ----
    char* base = (char*)d_ws;
    size_t off = 0;
    auto alloc = [&](size_t bytes) -> char* {
        char* p = base + off;
        off += (bytes + 255) & ~(size_t)255;
        return p;
    };
    ushort_t* Xb   = (ushort_t*)alloc((size_t)N * H2C * 2);  // bf16 x
    ushort_t* XWb  = (ushort_t*)alloc((size_t)N * H2C * 2);  // bf16 x@W0
    ushort_t* Bbb  = (ushort_t*)alloc((size_t)N * H2C * 2);  // bf16 layer-1 act
    ushort_t* Cbb  = (ushort_t*)alloc((size_t)N * HDC * 2);  // bf16 layer-2 gemm out
    ushort_t* W0T  = (ushort_t*)alloc((size_t)H2C * H2C * 2);
    ushort_t* W1T  = (ushort_t*)alloc((size_t)HDC * H2C * 2);
    float*    U    = (float*)alloc(258 * 4);
    int* rp1    = (int*)alloc((size_t)(N + 1) * 4);
    int* rp2    = (int*)alloc((size_t)(N + 1) * 4);
    int* rpD    = (int*)alloc((size_t)(N + 1) * 4);
    int* cursor = (int*)alloc((size_t)(N + 1) * 4);
    int* bsum   = (int*)alloc(1024 * 4);
    int*   ci1 = (int*)alloc((size_t)E * 4);
    float* cv1 = (float*)alloc((size_t)E * 4);
    int*   ci2 = (int*)alloc((size_t)E * 4);
    float* cv2 = (float*)alloc((size_t)E * 4);
    int*   ciD = (int*)alloc((size_t)ED * 4);
    float* cvD = (float*)alloc((size_t)ED * 4);

    float* out  = (float*)d_out;
    float* h1   = out;
    float* h2   = out + 1 * (size_t)N * HDC;
    float* h3   = out + 2 * (size_t)N * HDC;
    float* h4   = out + 3 * (size_t)N * HDC;
    float* beta = out + 4 * (size_t)N * HDC;

    const int nb = (N + 255) / 256;

    auto build_csr = [&](const int* row, const int* col, const float* val, int ne,
                         int* rp, int* ci, float* cv) {
        hipMemsetAsync(cursor, 0, (size_t)N * 4, stream);
        hist_kernel<<<dim3((ne + 255) / 256), 256, 0, stream>>>(row, ne, cursor);
        block_sum_kernel<<<dim3(nb), 256, 0, stream>>>(cursor, N, bsum);
        scan_bsum_kernel<<<1, 64, 0, stream>>>(bsum, nb);
        block_scan_kernel<<<dim3(nb), 256, 0, stream>>>(cursor, N, bsum, rp, ne);
        copy_int_kernel<<<dim3(nb), 256, 0, stream>>>(rp, cursor, N);
        scatter_kernel<<<dim3((ne + 255) / 256), 256, 0, stream>>>(row, col, val, ne, cursor, ci, cv);
    };

    gate_pre_kernel<<<1, HDC, 0, stream>>>(G1w, G1b, G2w, G2b, G3w, G3b, U);
    transpose_f2bf_kernel<<<dim3((H2C * H2C + 255) / 256), 256, 0, stream>>>(W0, W0T, H2C, H2C);
    transpose_f2bf_kernel<<<dim3((H2C * HDC + 255) / 256), 256, 0, stream>>>(W1, W1T, H2C, HDC);

    build_csr(a1r, a1c, a1v, E,  rp1, ci1, cv1);
    build_csr(a2r, a2c, a2v, E,  rp2, ci2, cv2);
    build_csr(dr,  dc,  dv,  ED, rpD, ciD, cvD);

    auto run_branch = [&](const int* rp, const int* ci, const float* cv, float* hout) {
        spmm_csr_f256<<<dim3((N + 3) / 4), 256, 0, stream>>>(rp, ci, cv, XWb, Bbb, b0, a0, N);
        gemm_bf16_mfma<<<dim3(HDC / 128, (N + 127) / 128), 256, 0, stream>>>(
            Bbb, W1T, Cbb, N, HDC, H2C);
        spmm_csr_f128<<<dim3((N + 3) / 4), 256, 0, stream>>>(rp, ci, cv, Cbb, hout, b1, a1p, N);
    };

    // x1 branch chain (h1, h3, h4 share x1 @ W0)
    f2bf_kernel<<<dim3(2048), 256, 0, stream>>>(x1, Xb, (long long)N * H2C / 4);
    gemm_bf16_mfma<<<dim3(H2C / 128, (N + 127) / 128), 256, 0, stream>>>(
        Xb, W0T, XWb, N, H2C, IN);
    run_branch(rp1, ci1, cv1, h1);
    run_branch(rp2, ci2, cv2, h3);
    run_branch(rpD, ciD, cvD, h4);

    // x2 branch (h2)
    f2bf_kernel<<<dim3(2048), 256, 0, stream>>>(x2, Xb, (long long)N * H2C / 4);
    gemm_bf16_mfma<<<dim3(H2C / 128, (N + 127) / 128), 256, 0, stream>>>(
        Xb, W0T, XWb, N, H2C, IN);
    run_branch(rp1, ci1, cv1, h2);

    beta_kernel<<<dim3((N + 255) / 256), 256, 0, stream>>>(h1, h3, deg, U, beta, N);
}

// Round 4
// 783.656 us; speedup vs baseline: 18.5128x; 1.3572x over previous
//
#include <hip/hip_runtime.h>
#include <hip/hip_bf16.h>

#define H2C 256   // 2*hidden
#define HDC 128   // hidden
#define GATEC 64

typedef unsigned short ushort_t;
typedef __attribute__((ext_vector_type(8))) __bf16 bf16x8;
typedef __attribute__((ext_vector_type(4))) float f32x4;

__device__ inline float bf2f(unsigned short v) {
    union { unsigned u; float f; } t; t.u = ((unsigned)v) << 16; return t.f;
}
__device__ inline unsigned short f2bf(float v) {
    __hip_bfloat16 b = __float2bfloat16(v);
    return *reinterpret_cast<unsigned short*>(&b);
}

__device__ inline void gload_lds16(const void* g, void* l) {
    __builtin_amdgcn_global_load_lds(
        (const __attribute__((address_space(1))) unsigned int*)g,
        (__attribute__((address_space(3))) unsigned int*)l, 16, 0, 0);
}

// ---------------- bf16 MFMA GEMM: C[M,Nn] = A[M,K] @ B, B given as BT[Nn,K] ----------------
__global__ __launch_bounds__(256)
void gemm_bf16_mfma(const ushort_t* __restrict__ A, const ushort_t* __restrict__ BT,
                    ushort_t* __restrict__ C, int M, int Nn, int K)
{
    __shared__ ushort_t Alds[128 * 64];
    __shared__ ushort_t Blds[128 * 64];
    const int tid  = threadIdx.x;
    const int w    = tid >> 6;
    const int lane = tid & 63;
    const int wr   = w >> 1;
    const int wc   = w & 1;
    const int bm   = blockIdx.y * 128;
    const int bn   = blockIdx.x * 128;

    f32x4 acc[4][4] = {};

    for (int k0 = 0; k0 < K; k0 += 64) {
        #pragma unroll
        for (int i = 0; i < 4; ++i) {
            const int lin = i * 256 + tid;
            const int r = lin >> 3, p = lin & 7;
            int rm = bm + r; if (rm >= M) rm = M - 1;
            const ushort_t* ga = A + (size_t)rm * K + k0 + ((p ^ (r & 7)) << 3);
            gload_lds16(ga, &Alds[i * 2048 + w * 512]);
        }
        #pragma unroll
        for (int i = 0; i < 4; ++i) {
            const int lin = i * 256 + tid;
            const int r = lin >> 3, p = lin & 7;
            const ushort_t* gb = BT + (size_t)(bn + r) * K + k0 + ((p ^ (r & 7)) << 3);
            gload_lds16(gb, &Blds[i * 2048 + w * 512]);
        }
        __syncthreads();
        #pragma unroll
        for (int kk = 0; kk < 2; ++kk) {
            bf16x8 af[4], bfr[4];
            #pragma unroll
            for (int m = 0; m < 4; ++m) {
                const int r = wr * 64 + m * 16 + (lane & 15);
                const int s = kk * 4 + (lane >> 4);
                af[m] = *reinterpret_cast<const bf16x8*>(&Alds[r * 64 + ((s ^ (r & 7)) << 3)]);
            }
            #pragma unroll
            for (int n = 0; n < 4; ++n) {
                const int r = wc * 64 + n * 16 + (lane & 15);
                const int s = kk * 4 + (lane >> 4);
                bfr[n] = *reinterpret_cast<const bf16x8*>(&Blds[r * 64 + ((s ^ (r & 7)) << 3)]);
            }
            #pragma unroll
            for (int m = 0; m < 4; ++m)
                #pragma unroll
                for (int n = 0; n < 4; ++n)
                    acc[m][n] = __builtin_amdgcn_mfma_f32_16x16x32_bf16(
                        af[m], bfr[n], acc[m][n], 0, 0, 0);
        }
        __syncthreads();
    }

    #pragma unroll
    for (int m = 0; m < 4; ++m) {
        const int row0 = bm + wr * 64 + m * 16 + ((lane >> 4) << 2);
        #pragma unroll
        for (int n = 0; n < 4; ++n) {
            const int col = bn + wc * 64 + n * 16 + (lane & 15);
            #pragma unroll
            for (int q = 0; q < 4; ++q) {
                const int row = row0 + q;
                if (row < M) C[(size_t)row * Nn + col] = f2bf(acc[m][n][q]);
            }
        }
    }
}

// ---------------- fp32 -> bf16 convert, two sources into one buffer ----------------
__global__ __launch_bounds__(256)
void f2bf_pair_kernel(const float* __restrict__ in1, const float* __restrict__ in2,
                      ushort_t* __restrict__ out, long long n4each)
{
    long long i = (long long)blockIdx.x * blockDim.x + threadIdx.x;
    const long long stride = (long long)gridDim.x * blockDim.x;
    for (; i < 2 * n4each; i += stride) {
        const float* src = (i < n4each) ? in1 : in2;
        const long long k = (i < n4each) ? i : i - n4each;
        const float4 v = reinterpret_cast<const float4*>(src)[k];
        ushort4 o;
        o.x = f2bf(v.x); o.y = f2bf(v.y); o.z = f2bf(v.z); o.w = f2bf(v.w);
        reinterpret_cast<ushort4*>(out)[i] = o;
    }
}

// ---------------- W[R,C] -> bf16 WT[C,R] ----------------
__global__ __launch_bounds__(256)
void transpose_f2bf_kernel(const float* __restrict__ W, ushort_t* __restrict__ WT, int R, int Ccols)
{
    const int i = blockIdx.x * blockDim.x + threadIdx.x;
    if (i >= R * Ccols) return;
    const int c = i / R, r = i % R;
    WT[(size_t)c * R + r] = f2bf(W[(size_t)r * Ccols + c]);
}

// ---------------- fused CSR build over 3 adjacencies (concatenated) ----------------
__global__ __launch_bounds__(256)
void hist3_kernel(const int* __restrict__ r0, const int* __restrict__ r1,
                  const int* __restrict__ rD, int E, int ED, int N, int* __restrict__ cnt)
{
    const long long i = (long long)blockIdx.x * blockDim.x + threadIdx.x;
    const long long tot = 2LL * E + ED;
    if (i >= tot) return;
    int idx;
    if (i < E)            idx = r0[i];
    else if (i < 2LL * E) idx = N + r1[i - E];
    else                  idx = 2 * N + rD[i - 2LL * E];
    atomicAdd(&cnt[idx], 1);
}

__global__ __launch_bounds__(256)
void block_sum_kernel(const int* __restrict__ cnt, int n, int* __restrict__ bsum)
{
    __shared__ int s[256];
    const int tid = threadIdx.x;
    const int i = blockIdx.x * 256 + tid;
    s[tid] = (i < n) ? cnt[i] : 0;
    __syncthreads();
    for (int o = 128; o > 0; o >>= 1) {
        if (tid < o) s[tid] += s[tid + o];
        __syncthreads();
    }
    if (tid == 0) bsum[blockIdx.x] = s[0];
}

__global__ void scan_bsum_kernel(int* __restrict__ bsum, int nb)
{
    if (threadIdx.x == 0) {
        int acc = 0;
        for (int b = 0; b < nb; ++b) { int t = bsum[b]; bsum[b] = acc; acc += t; }
    }
}

__global__ __launch_bounds__(256)
void block_scan_kernel(const int* __restrict__ cnt, int n, const int* __restrict__ bsum,
                       int* __restrict__ g, int tot)
{
    __shared__ int sh[256];
    const int tid = threadIdx.x;
    const int i = blockIdx.x * 256 + tid;
    const int v = (i < n) ? cnt[i] : 0;
    sh[tid] = v;
    __syncthreads();
    for (int o = 1; o < 256; o <<= 1) {
        int t = 0;
        if (tid >= o) t = sh[tid - o];
        __syncthreads();
        sh[tid] += t;
        __syncthreads();
    }
    if (i < n) g[i] = bsum[blockIdx.x] + sh[tid] - v;  // exclusive
    if (i == 0) g[n] = tot;
}

__global__ __launch_bounds__(256)
void copy_int_kernel(const int* __restrict__ src, int* __restrict__ dst, int n)
{
    const int i = blockIdx.x * 256 + threadIdx.x;
    if (i < n) dst[i] = src[i];
}

__global__ __launch_bounds__(256)
void scatter3_kernel(const int* __restrict__ r0, const int* __restrict__ c0, const float* __restrict__ v0,
                     const int* __restrict__ r1, const int* __restrict__ c1, const float* __restrict__ v1,
                     const int* __restrict__ rD, const int* __restrict__ cD, const float* __restrict__ vD,
                     int E, int ED, int N, int* __restrict__ cursor, int2* __restrict__ ecv)
{
    const long long i = (long long)blockIdx.x * blockDim.x + threadIdx.x;
    const long long tot = 2LL * E + ED;
    if (i >= tot) return;
    int idx, c; float v;
    if (i < E)            { idx = r0[i];            c = c0[i];            v = v0[i]; }
    else if (i < 2LL * E) { idx = N + r1[i - E];    c = c1[i - E];        v = v1[i - E]; }
    else                  { idx = 2 * N + rD[i - 2LL * E]; c = cD[i - 2LL * E]; v = vD[i - 2LL * E]; }
    const int p = atomicAdd(&cursor[idx], 1);
    ecv[p] = make_int2(c, __float_as_int(v));
}

// ---------------- CSR SpMM, F=256, fused bias+PReLU+ReLU, bf16 in/out, 4x unroll ----------------
__global__ __launch_bounds__(256)
void spmm_csr_f256(const int* __restrict__ rp, const int2* __restrict__ ecv,
                   const ushort_t* __restrict__ X, ushort_t* __restrict__ Y,
                   const float* __restrict__ bias, const float* __restrict__ ap, int n)
{
    const int r = blockIdx.x * 4 + (threadIdx.x >> 6);
    if (r >= n) return;
    const int lane = threadIdx.x & 63;
    const int s = rp[r], e = rp[r + 1];
    float4 acc = make_float4(0.f, 0.f, 0.f, 0.f);
    int j = s;
    for (; j + 3 < e; j += 4) {
        const int2 e0 = ecv[j], e1 = ecv[j + 1], e2 = ecv[j + 2], e3 = ecv[j + 3];
        const ushort4 x0 = *reinterpret_cast<const ushort4*>(X + (size_t)e0.x * H2C + lane * 4);
        const ushort4 x1 = *reinterpret_cast<const ushort4*>(X + (size_t)e1.x * H2C + lane * 4);
        const ushort4 x2 = *reinterpret_cast<const ushort4*>(X + (size_t)e2.x * H2C + lane * 4);
        const ushort4 x3 = *reinterpret_cast<const ushort4*>(X + (size_t)e3.x * H2C + lane * 4);
        const float v0 = __int_as_float(e0.y), v1 = __int_as_float(e1.y);
        const float v2 = __int_as_float(e2.y), v3 = __int_as_float(e3.y);
        acc.x += v0 * bf2f(x0.x) + v1 * bf2f(x1.x) + v2 * bf2f(x2.x) + v3 * bf2f(x3.x);
        acc.y += v0 * bf2f(x0.y) + v1 * bf2f(x1.y) + v2 * bf2f(x2.y) + v3 * bf2f(x3.y);
        acc.z += v0 * bf2f(x0.z) + v1 * bf2f(x1.z) + v2 * bf2f(x2.z) + v3 * bf2f(x3.z);
        acc.w += v0 * bf2f(x0.w) + v1 * bf2f(x1.w) + v2 * bf2f(x2.w) + v3 * bf2f(x3.w);
    }
    for (; j < e; ++j) {
        const int2 e0 = ecv[j];
        const float v0 = __int_as_float(e0.y);
        const ushort4 x0 = *reinterpret_cast<const ushort4*>(X + (size_t)e0.x * H2C + lane * 4);
        acc.x += v0 * bf2f(x0.x); acc.y += v0 * bf2f(x0.y);
        acc.z += v0 * bf2f(x0.z); acc.w += v0 * bf2f(x0.w);
    }
    const float a = ap[0];
    const float4 b = *reinterpret_cast<const float4*>(bias + lane * 4);
    float t;
    ushort4 o;
    t = acc.x + b.x; t = t >= 0.f ? t : a * t; o.x = f2bf(fmaxf(t, 0.f));
    t = acc.y + b.y; t = t >= 0.f ? t : a * t; o.y = f2bf(fmaxf(t, 0.f));
    t = acc.z + b.z; t = t >= 0.f ? t : a * t; o.z = f2bf(fmaxf(t, 0.f));
    t = acc.w + b.w; t = t >= 0.f ? t : a * t; o.w = f2bf(fmaxf(t, 0.f));
    *reinterpret_cast<ushort4*>(Y + (size_t)r * H2C + lane * 4) = o;
}

// ---------------- CSR SpMM, F=128, fused bias+PReLU, bf16 gather, fp32 out, 4x unroll ----------------
__global__ __launch_bounds__(256)
void spmm_csr_f128(const int* __restrict__ rp, const int2* __restrict__ ecv,
                   const ushort_t* __restrict__ X, float* __restrict__ Y,
                   const float* __restrict__ bias, const float* __restrict__ ap, int n)
{
    const int r = blockIdx.x * 4 + (threadIdx.x >> 6);
    if (r >= n) return;
    const int lane = threadIdx.x & 63;
    const int s = rp[r], e = rp[r + 1];
    float ax = 0.f, ay = 0.f;
    int j = s;
    for (; j + 3 < e; j += 4) {
        const int2 e0 = ecv[j], e1 = ecv[j + 1], e2 = ecv[j + 2], e3 = ecv[j + 3];
        const unsigned x0 = *reinterpret_cast<const unsigned*>(X + (size_t)e0.x * HDC + lane * 2);
        const unsigned x1 = *reinterpret_cast<const unsigned*>(X + (size_t)e1.x * HDC + lane * 2);
        const unsigned x2 = *reinterpret_cast<const unsigned*>(X + (size_t)e2.x * HDC + lane * 2);
        const unsigned x3 = *reinterpret_cast<const unsigned*>(X + (size_t)e3.x * HDC + lane * 2);
        const float v0 = __int_as_float(e0.y), v1 = __int_as_float(e1.y);
        const float v2 = __int_as_float(e2.y), v3 = __int_as_float(e3.y);
        ax += v0 * bf2f((ushort_t)(x0 & 0xffffu)) + v1 * bf2f((ushort_t)(x1 & 0xffffu))
            + v2 * bf2f((ushort_t)(x2 & 0xffffu)) + v3 * bf2f((ushort_t)(x3 & 0xffffu));
        ay += v0 * bf2f((ushort_t)(x0 >> 16)) + v1 * bf2f((ushort_t)(x1 >> 16))
            + v2 * bf2f((ushort_t)(x2 >> 16)) + v3 * bf2f((ushort_t)(x3 >> 16));
    }
    for (; j < e; ++j) {
        const int2 e0 = ecv[j];
        const float v0 = __int_as_float(e0.y);
        const unsigned x0 = *reinterpret_cast<const unsigned*>(X + (size_t)e0.x * HDC + lane * 2);
        ax += v0 * bf2f((ushort_t)(x0 & 0xffffu));
        ay += v0 * bf2f((ushort_t)(x0 >> 16));
    }
    const float a = ap[0];
    ax += bias[lane * 2 + 0];
    ay += bias[lane * 2 + 1];
    ax = ax >= 0.f ? ax : a * ax;
    ay = ay >= 0.f ? ay : a * ay;
    *reinterpret_cast<float2*>(Y + (size_t)r * HDC + lane * 2) = make_float2(ax, ay);
}

// ---------------- gate precompute ----------------
__global__ void gate_pre_kernel(const float* __restrict__ G1w, const float* __restrict__ G1b,
                                const float* __restrict__ G2w, const float* __restrict__ G2b,
                                const float* __restrict__ G3w, const float* __restrict__ G3b,
                                float* __restrict__ U)
{
    const int h = threadIdx.x;  // 0..127
    float s1 = 0.f, s2 = 0.f;
    for (int g = 0; g < GATEC; ++g) {
        s1 += G1w[h * GATEC + g] * G3w[g];
        s2 += G2w[h * GATEC + g] * G3w[GATEC + g];
    }
    U[h] = s1;
    U[HDC + h] = s2;
    if (h == 0) {
        float c = G3b[0];
        for (int g = 0; g < GATEC; ++g)
            c += G1b[g] * G3w[g] + G2b[g] * G3w[GATEC + g];
        U[2 * HDC] = c;
        U[2 * HDC + 1] = G3w[2 * GATEC];
    }
}

// ---------------- beta ----------------
__global__ __launch_bounds__(256)
void beta_kernel(const float* __restrict__ h1, const float* __restrict__ h3,
                 const float* __restrict__ deg, const float* __restrict__ U,
                 float* __restrict__ beta, int n)
{
    const int i = blockIdx.x * blockDim.x + threadIdx.x;
    if (i >= n) return;
    const float c = U[2 * HDC], wd = U[2 * HDC + 1];
    float s = c + wd * deg[i];
    const float4* h1p = reinterpret_cast<const float4*>(h1 + (size_t)i * HDC);
    const float4* h3p = reinterpret_cast<const float4*>(h3 + (size_t)i * HDC);
    const float4* u1p = reinterpret_cast<const float4*>(U);
    const float4* u2p = reinterpret_cast<const float4*>(U + HDC);
    #pragma unroll 8
    for (int j = 0; j < HDC / 4; ++j) {
        const float4 a = h1p[j], b = u1p[j];
        s += a.x * b.x + a.y * b.y + a.z * b.z + a.w * b.w;
        const float4 a2 = h3p[j], b2 = u2p[j];
        s += a2.x * b2.x + a2.y * b2.y + a2.z * b2.z + a2.w * b2.w;
    }
    beta[i] = 1.f / (1.f + expf(-s));
}

extern "C" void kernel_launch(void* const* d_in, const int* in_sizes, int n_in,
                              void* d_out, int out_size, void* d_ws, size_t ws_size,
                              hipStream_t stream)
{
    const float* x1  = (const float*)d_in[0];
    const float* x2  = (const float*)d_in[1];
    const int*   a1r = (const int*)d_in[2];
    const int*   a1c = (const int*)d_in[3];
    const float* a1v = (const float*)d_in[4];
    const int*   a2r = (const int*)d_in[5];
    const int*   a2c = (const int*)d_in[6];
    const float* a2v = (const float*)d_in[7];
    const int*   dr  = (const int*)d_in[8];
    const int*   dc  = (const int*)d_in[9];
    const float* dv  = (const float*)d_in[10];
    const float* deg = (const float*)d_in[11];
    const float* W0  = (const float*)d_in[12];
    const float* b0  = (const float*)d_in[13];
    const float* a0  = (const float*)d_in[14];
    const float* W1  = (const float*)d_in[15];
    const float* b1  = (const float*)d_in[16];
    const float* a1p = (const float*)d_in[17];
    const float* G1w = (const float*)d_in[18];
    const float* G1b = (const float*)d_in[19];
    const float* G2w = (const float*)d_in[20];
    const float* G2b = (const float*)d_in[21];
    const float* G3w = (const float*)d_in[22];
    const float* G3b = (const float*)d_in[23];

    const int E  = in_sizes[2];
    const int ED = in_sizes[8];
    const int N  = in_sizes[11];
    const int IN = in_sizes[0] / N;   // 256
    const long long TOT = 2LL * E + ED;

    // ---- workspace bump allocator (256 B aligned) ----
    char* base = (char*)d_ws;
    size_t off = 0;
    auto alloc = [&](size_t bytes) -> char* {
        char* p = base + off;
        off += (bytes + 255) & ~(size_t)255;
        return p;
    };
    // XW12b: bf16 [x1@W0 ; x2@W0], 2N x 256
    ushort_t* XW12b = (ushort_t*)alloc((size_t)2 * N * H2C * 2);
    // Region R: Xb12 (2N x 256 bf16) aliases (Bbb N x 256 bf16 + Cbb N x 128 bf16)
    char* R = alloc((size_t)2 * N * H2C * 2);
    ushort_t* Xb12 = (ushort_t*)R;
    ushort_t* Bbb  = (ushort_t*)R;
    ushort_t* Cbb  = (ushort_t*)(R + (size_t)N * H2C * 2);
    ushort_t* W0T  = (ushort_t*)alloc((size_t)H2C * H2C * 2);
    ushort_t* W1T  = (ushort_t*)alloc((size_t)HDC * H2C * 2);
    float*    U    = (float*)alloc(258 * 4);
    int*  cnt    = (int*)alloc((size_t)(3 * N) * 4);
    int*  g      = (int*)alloc((size_t)(3 * N + 1) * 4);
    int*  cursor = (int*)alloc((size_t)(3 * N) * 4);
    int*  bsum   = (int*)alloc(1024 * 4);
    int2* ecv    = (int2*)alloc((size_t)TOT * 8);

    float* out  = (float*)d_out;
    float* h1   = out;
    float* h2   = out + 1 * (size_t)N * HDC;
    float* h3   = out + 2 * (size_t)N * HDC;
    float* h4   = out + 3 * (size_t)N * HDC;
    float* beta = out + 4 * (size_t)N * HDC;

    const int nb3 = (3 * N + 255) / 256;

    // ---- small precomputes ----
    gate_pre_kernel<<<1, HDC, 0, stream>>>(G1w, G1b, G2w, G2b, G3w, G3b, U);
    transpose_f2bf_kernel<<<dim3((H2C * H2C + 255) / 256), 256, 0, stream>>>(W0, W0T, H2C, H2C);
    transpose_f2bf_kernel<<<dim3((H2C * HDC + 255) / 256), 256, 0, stream>>>(W1, W1T, H2C, HDC);

    // ---- fused CSR build (3 adjacencies concatenated) ----
    hipMemsetAsync(cnt, 0, (size_t)(3 * N) * 4, stream);
    hist3_kernel<<<dim3((unsigned)((TOT + 255) / 256)), 256, 0, stream>>>(a1r, a2r, dr, E, ED, N, cnt);
    block_sum_kernel<<<dim3(nb3), 256, 0, stream>>>(cnt, 3 * N, bsum);
    scan_bsum_kernel<<<1, 64, 0, stream>>>(bsum, nb3);
    block_scan_kernel<<<dim3(nb3), 256, 0, stream>>>(cnt, 3 * N, bsum, g, (int)TOT);
    copy_int_kernel<<<dim3(nb3), 256, 0, stream>>>(g, cursor, 3 * N);
    scatter3_kernel<<<dim3((unsigned)((TOT + 255) / 256)), 256, 0, stream>>>(
        a1r, a1c, a1v, a2r, a2c, a2v, dr, dc, dv, E, ED, N, cursor, ecv);

    // row-pointer views into the global exclusive scan (ecv positions are global)
    const int* rp1 = g;
    const int* rp2 = g + N;
    const int* rpD = g + 2 * N;

    // ---- x -> bf16 (both inputs), batched XW GEMM (2N rows) ----
    f2bf_pair_kernel<<<dim3(2048), 256, 0, stream>>>(x1, x2, Xb12, (long long)N * H2C / 4);
    gemm_bf16_mfma<<<dim3(H2C / 128, (2 * N + 127) / 128), 256, 0, stream>>>(
        Xb12, W0T, XW12b, 2 * N, H2C, IN);

    auto run_branch = [&](const int* rp, const ushort_t* Xsrc, float* hout) {
        spmm_csr_f256<<<dim3((N + 3) / 4), 256, 0, stream>>>(rp, ecv, Xsrc, Bbb, b0, a0, N);
        gemm_bf16_mfma<<<dim3(HDC / 128, (N + 127) / 128), 256, 0, stream>>>(
            Bbb, W1T, Cbb, N, HDC, H2C);
        spmm_csr_f128<<<dim3((N + 3) / 4), 256, 0, stream>>>(rp, ecv, Cbb, hout, b1, a1p, N);
    };

    const ushort_t* XW1b = XW12b;
    const ushort_t* XW2b = XW12b + (size_t)N * H2C;

    run_branch(rp1, XW1b, h1);
    run_branch(rp2, XW1b, h3);
    run_branch(rpD, XW1b, h4);
    run_branch(rp1, XW2b, h2);

    beta_kernel<<<dim3((N + 255) / 256), 256, 0, stream>>>(h1, h3, deg, U, beta, N);
}

// Round 6
// 762.178 us; speedup vs baseline: 19.0344x; 1.0282x over previous
//
#include <hip/hip_runtime.h>
#include <hip/hip_bf16.h>

#define H2C 256   // 2*hidden
#define HDC 128   // hidden
#define GATEC 64
#define NBUCK 8
#define NCHUNK 256   // chunks-per-bucket grid width (stride loop covers any bucket size)

typedef unsigned short ushort_t;
typedef __attribute__((ext_vector_type(8))) __bf16 bf16x8;
typedef __attribute__((ext_vector_type(4))) float f32x4;

__device__ inline float bf2f(unsigned short v) {
    union { unsigned u; float f; } t; t.u = ((unsigned)v) << 16; return t.f;
}
__device__ inline unsigned short f2bf(float v) {
    __hip_bfloat16 b = __float2bfloat16(v);
    return *reinterpret_cast<unsigned short*>(&b);
}

__device__ inline void gload_lds16(const void* g, void* l) {
    __builtin_amdgcn_global_load_lds(
        (const __attribute__((address_space(1))) unsigned int*)g,
        (__attribute__((address_space(3))) unsigned int*)l, 16, 0, 0);
}

// ---------------- bf16 MFMA GEMM: C[M,Nn] = A[M,K] @ B, B given as BT[Nn,K] ----------------
__global__ __launch_bounds__(256)
void gemm_bf16_mfma(const ushort_t* __restrict__ A, const ushort_t* __restrict__ BT,
                    ushort_t* __restrict__ C, int M, int Nn, int K)
{
    __shared__ ushort_t Alds[128 * 64];
    __shared__ ushort_t Blds[128 * 64];
    const int tid  = threadIdx.x;
    const int w    = tid >> 6;
    const int lane = tid & 63;
    const int wr   = w >> 1;
    const int wc   = w & 1;
    const int bm   = blockIdx.y * 128;
    const int bn   = blockIdx.x * 128;

    f32x4 acc[4][4] = {};

    for (int k0 = 0; k0 < K; k0 += 64) {
        #pragma unroll
        for (int i = 0; i < 4; ++i) {
            const int lin = i * 256 + tid;
            const int r = lin >> 3, p = lin & 7;
            int rm = bm + r; if (rm >= M) rm = M - 1;
            const ushort_t* ga = A + (size_t)rm * K + k0 + ((p ^ (r & 7)) << 3);
            gload_lds16(ga, &Alds[i * 2048 + w * 512]);
        }
        #pragma unroll
        for (int i = 0; i < 4; ++i) {
            const int lin = i * 256 + tid;
            const int r = lin >> 3, p = lin & 7;
            const ushort_t* gb = BT + (size_t)(bn + r) * K + k0 + ((p ^ (r & 7)) << 3);
            gload_lds16(gb, &Blds[i * 2048 + w * 512]);
        }
        __syncthreads();
        #pragma unroll
        for (int kk = 0; kk < 2; ++kk) {
            bf16x8 af[4], bfr[4];
            #pragma unroll
            for (int m = 0; m < 4; ++m) {
                const int r = wr * 64 + m * 16 + (lane & 15);
                const int s = kk * 4 + (lane >> 4);
                af[m] = *reinterpret_cast<const bf16x8*>(&Alds[r * 64 + ((s ^ (r & 7)) << 3)]);
            }
            #pragma unroll
            for (int n = 0; n < 4; ++n) {
                const int r = wc * 64 + n * 16 + (lane & 15);
                const int s = kk * 4 + (lane >> 4);
                bfr[n] = *reinterpret_cast<const bf16x8*>(&Blds[r * 64 + ((s ^ (r & 7)) << 3)]);
            }
            #pragma unroll
            for (int m = 0; m < 4; ++m)
                #pragma unroll
                for (int n = 0; n < 4; ++n)
                    acc[m][n] = __builtin_amdgcn_mfma_f32_16x16x32_bf16(
                        af[m], bfr[n], acc[m][n], 0, 0, 0);
        }
        __syncthreads();
    }

    #pragma unroll
    for (int m = 0; m < 4; ++m) {
        const int row0 = bm + wr * 64 + m * 16 + ((lane >> 4) << 2);
        #pragma unroll
        for (int n = 0; n < 4; ++n) {
            const int col = bn + wc * 64 + n * 16 + (lane & 15);
            #pragma unroll
            for (int q = 0; q < 4; ++q) {
                const int row = row0 + q;
                if (row < M) C[(size_t)row * Nn + col] = f2bf(acc[m][n][q]);
            }
        }
    }
}

// ---------------- fp32 -> bf16 convert, two sources into one buffer ----------------
__global__ __launch_bounds__(256)
void f2bf_pair_kernel(const float* __restrict__ in1, const float* __restrict__ in2,
                      ushort_t* __restrict__ out, long long n4each)
{
    long long i = (long long)blockIdx.x * blockDim.x + threadIdx.x;
    const long long stride = (long long)gridDim.x * blockDim.x;
    for (; i < 2 * n4each; i += stride) {
        const float* src = (i < n4each) ? in1 : in2;
        const long long k = (i < n4each) ? i : i - n4each;
        const float4 v = reinterpret_cast<const float4*>(src)[k];
        ushort4 o;
        o.x = f2bf(v.x); o.y = f2bf(v.y); o.z = f2bf(v.z); o.w = f2bf(v.w);
        reinterpret_cast<ushort4*>(out)[i] = o;
    }
}

// ---------------- W[R,C] -> bf16 WT[C,R] ----------------
__global__ __launch_bounds__(256)
void transpose_f2bf_kernel(const float* __restrict__ W, ushort_t* __restrict__ WT, int R, int Ccols)
{
    const int i = blockIdx.x * blockDim.x + threadIdx.x;
    if (i >= R * Ccols) return;
    const int c = i / R, r = i % R;
    WT[(size_t)c * R + r] = f2bf(W[(size_t)r * Ccols + c]);
}

// ---------------- fused CSR build over 3 adjacencies (concatenated virtual rows) ----------------
__global__ __launch_bounds__(256)
void hist3_kernel(const int* __restrict__ r0, const int* __restrict__ r1,
                  const int* __restrict__ rD, int E, int ED, int N, int* __restrict__ cnt)
{
    const long long i = (long long)blockIdx.x * blockDim.x + threadIdx.x;
    const long long tot = 2LL * E + ED;
    if (i >= tot) return;
    int idx;
    if (i < E)            idx = r0[i];
    else if (i < 2LL * E) idx = N + r1[i - E];
    else                  idx = 2 * N + rD[i - 2LL * E];
    atomicAdd(&cnt[idx], 1);
}

__global__ __launch_bounds__(256)
void block_sum_kernel(const int* __restrict__ cnt, int n, int* __restrict__ bsum)
{
    __shared__ int s[256];
    const int tid = threadIdx.x;
    const int i = blockIdx.x * 256 + tid;
    s[tid] = (i < n) ? cnt[i] : 0;
    __syncthreads();
    for (int o = 128; o > 0; o >>= 1) {
        if (tid < o) s[tid] += s[tid + o];
        __syncthreads();
    }
    if (tid == 0) bsum[blockIdx.x] = s[0];
}

__global__ void scan_bsum_kernel(int* __restrict__ bsum, int nb)
{
    if (threadIdx.x == 0) {
        int acc = 0;
        for (int b = 0; b < nb; ++b) { int t = bsum[b]; bsum[b] = acc; acc += t; }
    }
}

__global__ __launch_bounds__(256)
void block_scan_kernel(const int* __restrict__ cnt, int n, const int* __restrict__ bsum,
                       int* __restrict__ g, int tot)
{
    __shared__ int sh[256];
    const int tid = threadIdx.x;
    const int i = blockIdx.x * 256 + tid;
    const int v = (i < n) ? cnt[i] : 0;
    sh[tid] = v;
    __syncthreads();
    for (int o = 1; o < 256; o <<= 1) {
        int t = 0;
        if (tid >= o) t = sh[tid - o];
        __syncthreads();
        sh[tid] += t;
        __syncthreads();
    }
    if (i < n) g[i] = bsum[blockIdx.x] + sh[tid] - v;  // exclusive
    if (i == 0) g[n] = tot;
}

__global__ __launch_bounds__(256)
void copy_int_kernel(const int* __restrict__ src, int* __restrict__ dst, int n)
{
    const int i = blockIdx.x * 256 + threadIdx.x;
    if (i < n) dst[i] = src[i];
}

__global__ void init_cursorA_kernel(const int* __restrict__ g, int RPB, int NR,
                                    int* __restrict__ cursorA)
{
    const int t = threadIdx.x;
    if (t < NBUCK) {
        int idx = t * RPB; if (idx > NR) idx = NR;
        cursorA[t] = g[idx];
    }
}

// ---- Pass A: bucket edges by vrow/RPB into dense per-bucket staging (planar) ----
__global__ __launch_bounds__(256)
void bucket_stage_kernel(const int* __restrict__ r0, const int* __restrict__ c0, const float* __restrict__ v0,
                         const int* __restrict__ r1, const int* __restrict__ c1, const float* __restrict__ v1,
                         const int* __restrict__ rD, const int* __restrict__ cD, const float* __restrict__ vD,
                         int E, int ED, int N, int RPB,
                         int* __restrict__ cursorA,
                         int* __restrict__ srow, int* __restrict__ scol, float* __restrict__ sval)
{
    __shared__ int hcnt[NBUCK];
    __shared__ int hbase[NBUCK];
    const int tid = threadIdx.x;
    if (tid < NBUCK) hcnt[tid] = 0;
    __syncthreads();
    const long long base = (long long)blockIdx.x * 1024;
    const long long tot = 2LL * E + ED;
    int vr[4], cc[4], rk[4], bk[4];
    float vv[4];
    #pragma unroll
    for (int k = 0; k < 4; ++k) {
        const long long i = base + k * 256 + tid;
        vr[k] = -1;
        if (i < tot) {
            if (i < E)            { vr[k] = r0[i];                 cc[k] = c0[i];           vv[k] = v0[i]; }
            else if (i < 2LL * E) { vr[k] = N + r1[i - E];         cc[k] = c1[i - E];       vv[k] = v1[i - E]; }
            else                  { vr[k] = 2 * N + rD[i - 2LL * E]; cc[k] = cD[i - 2LL * E]; vv[k] = vD[i - 2LL * E]; }
            bk[k] = vr[k] / RPB;
            rk[k] = atomicAdd(&hcnt[bk[k]], 1);
        }
    }
    __syncthreads();
    if (tid < NBUCK) hbase[tid] = atomicAdd(&cursorA[tid], hcnt[tid]);
    __syncthreads();
    #pragma unroll
    for (int k = 0; k < 4; ++k) {
        if (vr[k] >= 0) {
            const int s = hbase[bk[k]] + rk[k];
            srow[s] = vr[k]; scol[s] = cc[k]; sval[s] = vv[k];
        }
    }
}

// ---- Pass B: fine scatter within bucket; block bid&7 == bucket -> XCD-local ecv slice ----
// Chunk-STRIDE loop so any bucket size is covered (round-5 crash fix).
__global__ __launch_bounds__(256)
void fine_scatter_kernel(const int* __restrict__ g, int RPB, int NR,
                         const int* __restrict__ srow, const int* __restrict__ scol,
                         const float* __restrict__ sval,
                         int* __restrict__ cursor, int2* __restrict__ ecv)
{
    const int b = blockIdx.x & (NBUCK - 1);
    int bsi = b * RPB;        if (bsi > NR) bsi = NR;
    int bei = (b + 1) * RPB;  if (bei > NR) bei = NR;
    const int bstart = g[bsi];
    const int bend   = g[bei];
    const int tid = threadIdx.x;
    for (int chunk = blockIdx.x >> 3; ; chunk += NCHUNK) {
        const int cbase = bstart + chunk * 1024;
        if (cbase >= bend) break;
        #pragma unroll
        for (int k = 0; k < 4; ++k) {
            const int i = cbase + k * 256 + tid;
            if (i < bend) {
                const int vr = srow[i];
                const int p = atomicAdd(&cursor[vr], 1);
                ecv[p] = make_int2(scol[i], __float_as_int(sval[i]));
            }
        }
    }
}

// ---------------- CSR SpMM, F=256, fused bias+PReLU+ReLU, bf16 in/out, 4x unroll ----------------
__global__ __launch_bounds__(256)
void spmm_csr_f256(const int* __restrict__ rp, const int2* __restrict__ ecv,
                   const ushort_t* __restrict__ X, ushort_t* __restrict__ Y,
                   const float* __restrict__ bias, const float* __restrict__ ap, int n)
{
    const int r = blockIdx.x * 4 + (threadIdx.x >> 6);
    if (r >= n) return;
    const int lane = threadIdx.x & 63;
    const int s = rp[r], e = rp[r + 1];
    float4 acc = make_float4(0.f, 0.f, 0.f, 0.f);
    int j = s;
    for (; j + 3 < e; j += 4) {
        const int2 e0 = ecv[j], e1 = ecv[j + 1], e2 = ecv[j + 2], e3 = ecv[j + 3];
        const ushort4 x0 = *reinterpret_cast<const ushort4*>(X + (size_t)e0.x * H2C + lane * 4);
        const ushort4 x1 = *reinterpret_cast<const ushort4*>(X + (size_t)e1.x * H2C + lane * 4);
        const ushort4 x2 = *reinterpret_cast<const ushort4*>(X + (size_t)e2.x * H2C + lane * 4);
        const ushort4 x3 = *reinterpret_cast<const ushort4*>(X + (size_t)e3.x * H2C + lane * 4);
        const float v0 = __int_as_float(e0.y), v1 = __int_as_float(e1.y);
        const float v2 = __int_as_float(e2.y), v3 = __int_as_float(e3.y);
        acc.x += v0 * bf2f(x0.x) + v1 * bf2f(x1.x) + v2 * bf2f(x2.x) + v3 * bf2f(x3.x);
        acc.y += v0 * bf2f(x0.y) + v1 * bf2f(x1.y) + v2 * bf2f(x2.y) + v3 * bf2f(x3.y);
        acc.z += v0 * bf2f(x0.z) + v1 * bf2f(x1.z) + v2 * bf2f(x2.z) + v3 * bf2f(x3.z);
        acc.w += v0 * bf2f(x0.w) + v1 * bf2f(x1.w) + v2 * bf2f(x2.w) + v3 * bf2f(x3.w);
    }
    for (; j < e; ++j) {
        const int2 e0 = ecv[j];
        const float v0 = __int_as_float(e0.y);
        const ushort4 x0 = *reinterpret_cast<const ushort4*>(X + (size_t)e0.x * H2C + lane * 4);
        acc.x += v0 * bf2f(x0.x); acc.y += v0 * bf2f(x0.y);
        acc.z += v0 * bf2f(x0.z); acc.w += v0 * bf2f(x0.w);
    }
    const float a = ap[0];
    const float4 b = *reinterpret_cast<const float4*>(bias + lane * 4);
    float t;
    ushort4 o;
    t = acc.x + b.x; t = t >= 0.f ? t : a * t; o.x = f2bf(fmaxf(t, 0.f));
    t = acc.y + b.y; t = t >= 0.f ? t : a * t; o.y = f2bf(fmaxf(t, 0.f));
    t = acc.z + b.z; t = t >= 0.f ? t : a * t; o.z = f2bf(fmaxf(t, 0.f));
    t = acc.w + b.w; t = t >= 0.f ? t : a * t; o.w = f2bf(fmaxf(t, 0.f));
    *reinterpret_cast<ushort4*>(Y + (size_t)r * H2C + lane * 4) = o;
}

// ---------------- CSR SpMM, F=128, fused bias+PReLU, bf16 gather, fp32 out, 4x unroll ----------------
__global__ __launch_bounds__(256)
void spmm_csr_f128(const int* __restrict__ rp, const int2* __restrict__ ecv,
                   const ushort_t* __restrict__ X, float* __restrict__ Y,
                   const float* __restrict__ bias, const float* __restrict__ ap, int n)
{
    const int r = blockIdx.x * 4 + (threadIdx.x >> 6);
    if (r >= n) return;
    const int lane = threadIdx.x & 63;
    const int s = rp[r], e = rp[r + 1];
    float ax = 0.f, ay = 0.f;
    int j = s;
    for (; j + 3 < e; j += 4) {
        const int2 e0 = ecv[j], e1 = ecv[j + 1], e2 = ecv[j + 2], e3 = ecv[j + 3];
        const unsigned x0 = *reinterpret_cast<const unsigned*>(X + (size_t)e0.x * HDC + lane * 2);
        const unsigned x1 = *reinterpret_cast<const unsigned*>(X + (size_t)e1.x * HDC + lane * 2);
        const unsigned x2 = *reinterpret_cast<const unsigned*>(X + (size_t)e2.x * HDC + lane * 2);
        const unsigned x3 = *reinterpret_cast<const unsigned*>(X + (size_t)e3.x * HDC + lane * 2);
        const float v0 = __int_as_float(e0.y), v1 = __int_as_float(e1.y);
        const float v2 = __int_as_float(e2.y), v3 = __int_as_float(e3.y);
        ax += v0 * bf2f((ushort_t)(x0 & 0xffffu)) + v1 * bf2f((ushort_t)(x1 & 0xffffu))
            + v2 * bf2f((ushort_t)(x2 & 0xffffu)) + v3 * bf2f((ushort_t)(x3 & 0xffffu));
        ay += v0 * bf2f((ushort_t)(x0 >> 16)) + v1 * bf2f((ushort_t)(x1 >> 16))
            + v2 * bf2f((ushort_t)(x2 >> 16)) + v3 * bf2f((ushort_t)(x3 >> 16));
    }
    for (; j < e; ++j) {
        const int2 e0 = ecv[j];
        const float v0 = __int_as_float(e0.y);
        const unsigned x0 = *reinterpret_cast<const unsigned*>(X + (size_t)e0.x * HDC + lane * 2);
        ax += v0 * bf2f((ushort_t)(x0 & 0xffffu));
        ay += v0 * bf2f((ushort_t)(x0 >> 16));
    }
    const float a = ap[0];
    ax += bias[lane * 2 + 0];
    ay += bias[lane * 2 + 1];
    ax = ax >= 0.f ? ax : a * ax;
    ay = ay >= 0.f ? ay : a * ay;
    *reinterpret_cast<float2*>(Y + (size_t)r * HDC + lane * 2) = make_float2(ax, ay);
}

// ---------------- gate precompute ----------------
__global__ void gate_pre_kernel(const float* __restrict__ G1w, const float* __restrict__ G1b,
                                const float* __restrict__ G2w, const float* __restrict__ G2b,
                                const float* __restrict__ G3w, const float* __restrict__ G3b,
                                float* __restrict__ U)
{
    const int h = threadIdx.x;  // 0..127
    float s1 = 0.f, s2 = 0.f;
    for (int g = 0; g < GATEC; ++g) {
        s1 += G1w[h * GATEC + g] * G3w[g];
        s2 += G2w[h * GATEC + g] * G3w[GATEC + g];
    }
    U[h] = s1;
    U[HDC + h] = s2;
    if (h == 0) {
        float c = G3b[0];
        for (int g = 0; g < GATEC; ++g)
            c += G1b[g] * G3w[g] + G2b[g] * G3w[GATEC + g];
        U[2 * HDC] = c;
        U[2 * HDC + 1] = G3w[2 * GATEC];
    }
}

// ---------------- beta ----------------
__global__ __launch_bounds__(256)
void beta_kernel(const float* __restrict__ h1, const float* __restrict__ h3,
                 const float* __restrict__ deg, const float* __restrict__ U,
                 float* __restrict__ beta, int n)
{
    const int i = blockIdx.x * blockDim.x + threadIdx.x;
    if (i >= n) return;
    const float c = U[2 * HDC], wd = U[2 * HDC + 1];
    float s = c + wd * deg[i];
    const float4* h1p = reinterpret_cast<const float4*>(h1 + (size_t)i * HDC);
    const float4* h3p = reinterpret_cast<const float4*>(h3 + (size_t)i * HDC);
    const float4* u1p = reinterpret_cast<const float4*>(U);
    const float4* u2p = reinterpret_cast<const float4*>(U + HDC);
    #pragma unroll 8
    for (int j = 0; j < HDC / 4; ++j) {
        const float4 a = h1p[j], b = u1p[j];
        s += a.x * b.x + a.y * b.y + a.z * b.z + a.w * b.w;
        const float4 a2 = h3p[j], b2 = u2p[j];
        s += a2.x * b2.x + a2.y * b2.y + a2.z * b2.z + a2.w * b2.w;
    }
    beta[i] = 1.f / (1.f + expf(-s));
}

extern "C" void kernel_launch(void* const* d_in, const int* in_sizes, int n_in,
                              void* d_out, int out_size, void* d_ws, size_t ws_size,
                              hipStream_t stream)
{
    const float* x1  = (const float*)d_in[0];
    const float* x2  = (const float*)d_in[1];
    const int*   a1r = (const int*)d_in[2];
    const int*   a1c = (const int*)d_in[3];
    const float* a1v = (const float*)d_in[4];
    const int*   a2r = (const int*)d_in[5];
    const int*   a2c = (const int*)d_in[6];
    const float* a2v = (const float*)d_in[7];
    const int*   dr  = (const int*)d_in[8];
    const int*   dc  = (const int*)d_in[9];
    const float* dv  = (const float*)d_in[10];
    const float* deg = (const float*)d_in[11];
    const float* W0  = (const float*)d_in[12];
    const float* b0  = (const float*)d_in[13];
    const float* a0  = (const float*)d_in[14];
    const float* W1  = (const float*)d_in[15];
    const float* b1  = (const float*)d_in[16];
    const float* a1p = (const float*)d_in[17];
    const float* G1w = (const float*)d_in[18];
    const float* G1b = (const float*)d_in[19];
    const float* G2w = (const float*)d_in[20];
    const float* G2b = (const float*)d_in[21];
    const float* G3w = (const float*)d_in[22];
    const float* G3b = (const float*)d_in[23];

    const int E  = in_sizes[2];
    const int ED = in_sizes[8];
    const int N  = in_sizes[11];
    const int IN = in_sizes[0] / N;   // 256
    const long long TOT = 2LL * E + ED;
    const int NR  = 3 * N;
    const int RPB = (NR + NBUCK - 1) / NBUCK;

    // ---- workspace bump allocator (256 B aligned) ----
    char* base = (char*)d_ws;
    size_t off = 0;
    auto alloc = [&](size_t bytes) -> char* {
        char* p = base + off;
        off += (bytes + 255) & ~(size_t)255;
        return p;
    };
    // XW12b: bf16 [x1@W0 ; x2@W0], 2N x 256
    ushort_t* XW12b = (ushort_t*)alloc((size_t)2 * N * H2C * 2);
    // Region R: staging (srow/scol/sval, 3*TOT*4 B) then Xb12 (2N*256 bf16) then Bbb+Cbb
    char* R = alloc((size_t)2 * N * H2C * 2);
    int*      srow = (int*)R;
    int*      scol = (int*)(R + (size_t)TOT * 4);
    float*    sval = (float*)(R + (size_t)TOT * 8);
    ushort_t* Xb12 = (ushort_t*)R;
    ushort_t* Bbb  = (ushort_t*)R;
    ushort_t* Cbb  = (ushort_t*)(R + (size_t)N * H2C * 2);
    ushort_t* W0T  = (ushort_t*)alloc((size_t)H2C * H2C * 2);
    ushort_t* W1T  = (ushort_t*)alloc((size_t)HDC * H2C * 2);
    float*    U    = (float*)alloc(258 * 4);
    int*  cnt     = (int*)alloc((size_t)NR * 4);
    int*  g       = (int*)alloc((size_t)(NR + 1) * 4);
    int*  cursor  = (int*)alloc((size_t)NR * 4);
    int*  bsum    = (int*)alloc(1024 * 4);
    int*  cursorA = (int*)alloc(NBUCK * 4);
    int2* ecv     = (int2*)alloc((size_t)TOT * 8);

    float* out  = (float*)d_out;
    float* h1   = out;
    float* h2   = out + 1 * (size_t)N * HDC;
    float* h3   = out + 2 * (size_t)N * HDC;
    float* h4   = out + 3 * (size_t)N * HDC;
    float* beta = out + 4 * (size_t)N * HDC;

    const int nb3 = (NR + 255) / 256;

    // ---- small precomputes ----
    gate_pre_kernel<<<1, HDC, 0, stream>>>(G1w, G1b, G2w, G2b, G3w, G3b, U);
    transpose_f2bf_kernel<<<dim3((H2C * H2C + 255) / 256), 256, 0, stream>>>(W0, W0T, H2C, H2C);
    transpose_f2bf_kernel<<<dim3((H2C * HDC + 255) / 256), 256, 0, stream>>>(W1, W1T, H2C, HDC);

    // ---- CSR build: hist + scan ----
    hipMemsetAsync(cnt, 0, (size_t)NR * 4, stream);
    hist3_kernel<<<dim3((unsigned)((TOT + 255) / 256)), 256, 0, stream>>>(a1r, a2r, dr, E, ED, N, cnt);
    block_sum_kernel<<<dim3(nb3), 256, 0, stream>>>(cnt, NR, bsum);
    scan_bsum_kernel<<<1, 64, 0, stream>>>(bsum, nb3);
    block_scan_kernel<<<dim3(nb3), 256, 0, stream>>>(cnt, NR, bsum, g, (int)TOT);
    copy_int_kernel<<<dim3(nb3), 256, 0, stream>>>(g, cursor, NR);

    // ---- two-phase scatter ----
    init_cursorA_kernel<<<1, 64, 0, stream>>>(g, RPB, NR, cursorA);
    bucket_stage_kernel<<<dim3((unsigned)((TOT + 1023) / 1024)), 256, 0, stream>>>(
        a1r, a1c, a1v, a2r, a2c, a2v, dr, dc, dv, E, ED, N, RPB, cursorA, srow, scol, sval);
    fine_scatter_kernel<<<dim3(NBUCK * NCHUNK), 256, 0, stream>>>(
        g, RPB, NR, srow, scol, sval, cursor, ecv);

    // row-pointer views into the global exclusive scan (ecv positions are global)
    const int* rp1 = g;
    const int* rp2 = g + N;
    const int* rpD = g + 2 * N;

    // ---- x -> bf16 (both inputs), batched XW GEMM (2N rows) ----
    f2bf_pair_kernel<<<dim3(2048), 256, 0, stream>>>(x1, x2, Xb12, (long long)N * H2C / 4);
    gemm_bf16_mfma<<<dim3(H2C / 128, (2 * N + 127) / 128), 256, 0, stream>>>(
        Xb12, W0T, XW12b, 2 * N, H2C, IN);

    auto run_branch = [&](const int* rp, const ushort_t* Xsrc, float* hout) {
        spmm_csr_f256<<<dim3((N + 3) / 4), 256, 0, stream>>>(rp, ecv, Xsrc, Bbb, b0, a0, N);
        gemm_bf16_mfma<<<dim3(HDC / 128, (N + 127) / 128), 256, 0, stream>>>(
            Bbb, W1T, Cbb, N, HDC, H2C);
        spmm_csr_f128<<<dim3((N + 3) / 4), 256, 0, stream>>>(rp, ecv, Cbb, hout, b1, a1p, N);
    };

    const ushort_t* XW1b = XW12b;
    const ushort_t* XW2b = XW12b + (size_t)N * H2C;

    run_branch(rp1, XW1b, h1);
    run_branch(rp2, XW1b, h3);
    run_branch(rpD, XW1b, h4);
    run_branch(rp1, XW2b, h2);

    beta_kernel<<<dim3((N + 255) / 256), 256, 0, stream>>>(h1, h3, deg, U, beta, N);
}